// Round 1
// baseline (333.660 us; speedup 1.0000x reference)
//
#include <hip/hip_runtime.h>
#include <stdint.h>

#define D_MODEL 1024
#define NH 16
#define DH 64
#define TSEQ 2048
#define BATCH 4
#define MTOT (BATCH*TSEQ)
#define NQ (MTOT*D_MODEL)      // elements in Q/K/VT/AO and in x
#define WSZ (D_MODEL*D_MODEL)  // elements in each weight matrix
// SCALE * log2(e), pre-folded into Q at the qkv epilogue
#define QSCALE 0.18033688f

typedef __attribute__((ext_vector_type(8))) short bf16x8;
typedef __attribute__((ext_vector_type(8))) unsigned short u16x8;
typedef __attribute__((ext_vector_type(4))) float f32x4;
typedef __attribute__((ext_vector_type(2))) float f32x2;
typedef unsigned short u16;
typedef unsigned int u32;

__device__ __forceinline__ void gl_lds16(const void* g, void* l) {
  __builtin_amdgcn_global_load_lds(
      (__attribute__((address_space(1))) void*)g,
      (__attribute__((address_space(3))) void*)l, 16, 0, 0);
}
__device__ __forceinline__ u16 f2bf(float f) {
  u32 u = __builtin_bit_cast(u32, f);
  u = u + 0x7fffu + ((u >> 16) & 1u);
  return (u16)(u >> 16);
}
__device__ __forceinline__ float bf2f(u16 b) {
  u32 u = ((u32)b) << 16;
  return __builtin_bit_cast(float, u);
}
// packed bf16 convert: lo16 = bf16(lo), hi16 = bf16(hi). One VALU op vs 3.
__device__ __forceinline__ u32 cvtpk(float lo, float hi) {
  u32 r;
  asm("v_cvt_pk_bf16_f32 %0, %1, %2" : "=v"(r) : "v"(lo), "v"(hi));
  return r;
}

// ---------------------------------------------------------------------------
// Kernel 0: input dtype detection (1 = bf16, 0 = fp32). Round-4 verified.
// ---------------------------------------------------------------------------
__global__ __launch_bounds__(256) void detect_dtype(
    const u32* __restrict__ wq_raw, int* __restrict__ flag)
{
  __shared__ int cnt;
  if (threadIdx.x == 0) cnt = 0;
  __syncthreads();
  int c = 0;
  for (int i = threadIdx.x; i < 2048; i += 256) {
    const u32 e = (wq_raw[i] >> 7) & 0xFFu;
    if (e >= 90u && e <= 126u) ++c;
  }
  atomicAdd(&cnt, c);
  __syncthreads();
  if (threadIdx.x == 0) *flag = (cnt > 1024) ? 1 : 0;
}

// ---------------------------------------------------------------------------
// Kernel 0b: convert inputs to bf16. seg 0 = x -> d_out low half (fp32 only),
// 1..4 = Wq,Wk,Wv,Wo -> d_ws.
// ---------------------------------------------------------------------------
__global__ __launch_bounds__(256) void convert_inputs(
    const void* __restrict__ x, const void* __restrict__ wq,
    const void* __restrict__ wk, const void* __restrict__ wv,
    const void* __restrict__ wo,
    u16* __restrict__ xb, u16* __restrict__ wqb, u16* __restrict__ wkb,
    u16* __restrict__ wvb, u16* __restrict__ wob,
    const int* __restrict__ flag_p)
{
  const int flag = *flag_p;
  const int seg = blockIdx.y;
  const void* src; u16* dst; int n;
  switch (seg) {
    case 0:  src = x;  dst = xb;  n = NQ;  break;
    case 1:  src = wq; dst = wqb; n = WSZ; break;
    case 2:  src = wk; dst = wkb; n = WSZ; break;
    case 3:  src = wv; dst = wvb; n = WSZ; break;
    default: src = wo; dst = wob; n = WSZ; break;
  }
  if (flag && seg == 0) return;
  const int idx = (blockIdx.x * 256 + threadIdx.x) * 8;
  if (idx >= n) return;
  if (flag) {
    *(u16x8*)(dst + idx) = *(const u16x8*)((const u16*)src + idx);
  } else {
    const float4 f0 = *(const float4*)((const float*)src + idx);
    const float4 f1 = *(const float4*)((const float*)src + idx + 4);
    union { u16 s[8]; u16x8 v; } u;
    u.s[0] = f2bf(f0.x); u.s[1] = f2bf(f0.y); u.s[2] = f2bf(f0.z); u.s[3] = f2bf(f0.w);
    u.s[4] = f2bf(f1.x); u.s[5] = f2bf(f1.y); u.s[6] = f2bf(f1.z); u.s[7] = f2bf(f1.w);
    *(u16x8*)(dst + idx) = u.v;
  }
}

// ---------------------------------------------------------------------------
// Kernel 1: QKV projection. BK=64 via TWO BK=32 buffers per barrier-pair
// (keeps conflict-free 32-col layout + gl_lds contiguity; 32 KB LDS).
// z=0 -> Q^T [B,H,64,T] (pre-scaled); z=1 -> K [B,H,T,64]; z=2 -> V^T.
// ---------------------------------------------------------------------------
__global__ __launch_bounds__(256) void qkv_gemm(
    const int* __restrict__ flag_p, const u16* __restrict__ x_raw,
    u16* __restrict__ dout,
    const u16* __restrict__ Wq, const u16* __restrict__ Wk,
    const u16* __restrict__ Wv,
    u16* __restrict__ Ko, u16* __restrict__ VTo)
{
  __shared__ __align__(16) u16 As[2 * 128 * 32];
  __shared__ __align__(16) u16 Bs[2 * 128 * 32];
  const int flag = *flag_p;
  const u16* __restrict__ X = flag ? x_raw : dout;  // converted x in dout low
  u16* __restrict__ QTo = flag ? dout : dout + NQ;
  const int t = threadIdx.x;
  const int z = blockIdx.z;
  const u16* __restrict__ W = (z == 0) ? Wq : (z == 1) ? Wk : Wv;
  const int m0 = blockIdx.x * 128;
  const int n0 = blockIdx.y * 128;
  const int wave = t >> 6, lane = t & 63;
  const int wm = (wave >> 1) * 64, wn = (wave & 1) * 64;
  const int lr = lane & 15, kg = (lane >> 4) * 8;

  const int srow0 = t >> 2, skc = (t & 3) * 8;
  const int srow1 = srow0 + 64;
  const u16* a0 = X + (size_t)(m0 + srow0) * D_MODEL + skc;
  const u16* a1 = X + (size_t)(m0 + srow1) * D_MODEL + skc;
  const u16* b0 = W + (size_t)(n0 + srow0) * D_MODEL + skc;
  const u16* b1 = W + (size_t)(n0 + srow1) * D_MODEL + skc;

  f32x4 acc[4][4] = {};

  for (int kt = 0; kt < D_MODEL / 64; ++kt) {
    gl_lds16(a0,      &As[t * 8]);
    gl_lds16(a1,      &As[(t + 256) * 8]);
    gl_lds16(a0 + 32, &As[4096 + t * 8]);
    gl_lds16(a1 + 32, &As[4096 + (t + 256) * 8]);
    gl_lds16(b0,      &Bs[t * 8]);
    gl_lds16(b1,      &Bs[(t + 256) * 8]);
    gl_lds16(b0 + 32, &Bs[4096 + t * 8]);
    gl_lds16(b1 + 32, &Bs[4096 + (t + 256) * 8]);
    a0 += 64; a1 += 64; b0 += 64; b1 += 64;
    __syncthreads();
#pragma unroll
    for (int h = 0; h < 2; ++h) {
      bf16x8 af[4], bfr[4];
#pragma unroll
      for (int i = 0; i < 4; ++i)
        af[i] = *(const bf16x8*)&As[h * 4096 + (wm + i * 16 + lr) * 32 + kg];
#pragma unroll
      for (int j = 0; j < 4; ++j)
        bfr[j] = *(const bf16x8*)&Bs[h * 4096 + (wn + j * 16 + lr) * 32 + kg];
#pragma unroll
      for (int i = 0; i < 4; ++i)
#pragma unroll
        for (int j = 0; j < 4; ++j)
          acc[i][j] = __builtin_amdgcn_mfma_f32_16x16x32_bf16(af[i], bfr[j], acc[i][j], 0, 0, 0);
    }
    __syncthreads();
  }

  // C/D layout: col = lane&15, row = (lane>>4)*4 + reg
  const int bidx = m0 >> 11;
  if (z == 1) {
    // K: [B,H,T,64], scalar stores (d-contiguous rows for flash staging)
#pragma unroll
    for (int i = 0; i < 4; ++i) {
      const int rowg = m0 + wm + i * 16 + ((lane >> 4) << 2);
      const int tq = rowg & (TSEQ - 1);
#pragma unroll
      for (int j = 0; j < 4; ++j) {
        const int colg = n0 + wn + j * 16 + lr;
        const int h = colg >> 6, d = colg & 63;
        u16* dst = Ko + ((size_t)(bidx * NH + h) * TSEQ + tq) * DH + d;
#pragma unroll
        for (int r = 0; r < 4; ++r)
          dst[(size_t)r * DH] = f2bf(acc[i][j][r]);
      }
    }
  } else {
    // Q^T (scaled) and V^T: [B,H,64,T], vectorized 8B stores along t
    u16* O = (z == 0) ? QTo : VTo;
    const float sc = (z == 0) ? QSCALE : 1.0f;
#pragma unroll
    for (int i = 0; i < 4; ++i) {
      const int rowg = m0 + wm + i * 16 + ((lane >> 4) << 2);
      const int tq = rowg & (TSEQ - 1);  // multiple of 4 -> 8B aligned
#pragma unroll
      for (int j = 0; j < 4; ++j) {
        const int colg = n0 + wn + j * 16 + lr;
        const int h = colg >> 6, d = colg & 63;
        union { u16 s[4]; uint2 v; } u;
#pragma unroll
        for (int r = 0; r < 4; ++r) u.s[r] = f2bf(acc[i][j][r] * sc);
        *(uint2*)&O[((size_t)(bidx * NH + h) * DH + d) * TSEQ + tq] = u.v;
      }
    }
  }
}

// ---------------------------------------------------------------------------
// Kernel 2: flash attention, 128 q-rows per block, no-max softmax.
// ROUND-1 CHANGE: double-buffered K/V staging with a SINGLE barrier per tile.
// Schedule per tile: barrier -> issue gl_lds for tile t+1 into buf^1 ->
// compute buf cur. The compiler's automatic vmcnt(0)-before-s_barrier then
// waits on loads that had a full compute phase to land (near-free), instead
// of serializing the global latency every tile. WAR hazard on buf^1 is
// covered by the same barrier (all waves passed it => finished compute t-1,
// the last reader of buf^1). LDS 51.6 KB -> 3 blocks/CU.
// XCD-locality: grid = (64 bh, 16 qblk) so linear id % 8 == bh % 8.
// ---------------------------------------------------------------------------
__global__ __launch_bounds__(256) void flash_attn(
    const int* __restrict__ flag_p, const u16* __restrict__ dout,
    const u16* __restrict__ K, const u16* __restrict__ VT,
    u16* __restrict__ AO)
{
  __shared__ __align__(16) u16 Ks[2][2 * 64 * 32];  // [buf][half][64 keys][32 d]
  __shared__ __align__(16) u16 Vs[2][2 * 64 * 32];  // [buf][half][64 d][32 keys]
  __shared__ __align__(16) u16 Ps[4 * 32 * 72];     // per-wave [32 q][64+8 keys]
  __shared__ float Ls[4 * 32];
  const int flag = *flag_p;
  const u16* __restrict__ QT = flag ? dout : dout + NQ;
  const int t = threadIdx.x;
  const int wave = t >> 6, lane = t & 63;
  const int lr = lane & 15, g = lane >> 4, kg = g * 8;
  const int bh = blockIdx.x;          // fastest grid dim -> XCD = bh % 8
  const int q0 = blockIdx.y * 128;
  const u16* __restrict__ QTh = QT + (size_t)bh * DH * TSEQ;  // [64 d][T]
  const u16* __restrict__ Kh = K + (size_t)bh * TSEQ * DH;
  const u16* __restrict__ Vh = VT + (size_t)bh * DH * TSEQ;

  // Two Q B-fragments per wave (q-sets A/B, 16 q each), gathered from Q^T
  // once per kernel: 32 strided scalar loads.
  const int qiA = q0 + wave * 32 + lr;
  union { u16 s[8]; bf16x8 v; } qa0, qa1, qb0, qb1;
#pragma unroll
  for (int j = 0; j < 8; ++j) {
    qa0.s[j] = QTh[(size_t)(kg + j) * TSEQ + qiA];
    qa1.s[j] = QTh[(size_t)(32 + kg + j) * TSEQ + qiA];
    qb0.s[j] = QTh[(size_t)(kg + j) * TSEQ + qiA + 16];
    qb1.s[j] = QTh[(size_t)(32 + kg + j) * TSEQ + qiA + 16];
  }
  const bf16x8 qfA0 = qa0.v, qfA1 = qa1.v, qfB0 = qb0.v, qfB1 = qb1.v;

  f32x4 accA[4] = {}, accB[4] = {};
  f32x2 lsA0 = {0.f, 0.f}, lsA1 = {0.f, 0.f};
  f32x2 lsB0 = {0.f, 0.f}, lsB1 = {0.f, 0.f};

  const int srow = t >> 2, skc = (t & 3) * 8;
  const u16* kb = Kh + (size_t)srow * DH + skc;
  const u16* vb = Vh + (size_t)srow * TSEQ + skc;
  u16* const pw  = &Ps[wave * 32 * 72];        // q-set A rows 0..15
  u16* const pwB = pw + 16 * 72;               // q-set B rows 16..31

  // prologue: prefetch tile 0 into buffer 0
  gl_lds16(kb,      &Ks[0][t * 8]);          // keys, d 0..31
  gl_lds16(kb + 32, &Ks[0][(t + 256) * 8]);  // keys, d 32..63
  gl_lds16(vb,      &Vs[0][t * 8]);          // [d][keys 0..31]
  gl_lds16(vb + 32, &Vs[0][(t + 256) * 8]);  // [d][keys 32..63]
  kb += 64 * DH; vb += 64;

  int cur = 0;
  for (int j0 = 0; j0 < TSEQ; j0 += 64) {
    // single barrier per tile: drains cur-buf loads (issued a full tile ago)
    // and guarantees everyone is done reading buf^1 before we overwrite it.
    __syncthreads();
    if (j0 + 64 < TSEQ) {
      gl_lds16(kb,      &Ks[cur ^ 1][t * 8]);
      gl_lds16(kb + 32, &Ks[cur ^ 1][(t + 256) * 8]);
      gl_lds16(vb,      &Vs[cur ^ 1][t * 8]);
      gl_lds16(vb + 32, &Vs[cur ^ 1][(t + 256) * 8]);
      kb += 64 * DH; vb += 64;
    }
    const u16* __restrict__ Kc = Ks[cur];
    const u16* __restrict__ Vc = Vs[cur];

    // S^T tiles: C col = q (lr), row = key = jn*16 + g*4 + r
#pragma unroll
    for (int jn = 0; jn < 4; ++jn) {
      const bf16x8 kf0 = *(const bf16x8*)&Kc[(jn * 16 + lr) * 32 + kg];
      const bf16x8 kf1 = *(const bf16x8*)&Kc[2048 + (jn * 16 + lr) * 32 + kg];
      f32x4 sA = {}, sB = {};
      sA = __builtin_amdgcn_mfma_f32_16x16x32_bf16(kf0, qfA0, sA, 0, 0, 0);
      sA = __builtin_amdgcn_mfma_f32_16x16x32_bf16(kf1, qfA1, sA, 0, 0, 0);
      sB = __builtin_amdgcn_mfma_f32_16x16x32_bf16(kf0, qfB0, sB, 0, 0, 0);
      sB = __builtin_amdgcn_mfma_f32_16x16x32_bf16(kf1, qfB1, sB, 0, 0, 0);
      const float a0 = __builtin_exp2f(sA[0]);
      const float a1 = __builtin_exp2f(sA[1]);
      const float a2 = __builtin_exp2f(sA[2]);
      const float a3 = __builtin_exp2f(sA[3]);
      const float b0 = __builtin_exp2f(sB[0]);
      const float b1 = __builtin_exp2f(sB[1]);
      const float b2 = __builtin_exp2f(sB[2]);
      const float b3 = __builtin_exp2f(sB[3]);
      lsA0 += (f32x2){a0, a1}; lsA1 += (f32x2){a2, a3};
      lsB0 += (f32x2){b0, b1}; lsB1 += (f32x2){b2, b3};
      uint2 wA, wB;
      wA.x = cvtpk(a0, a1); wA.y = cvtpk(a2, a3);
      wB.x = cvtpk(b0, b1); wB.y = cvtpk(b2, b3);
      *(uint2*)&pw [lr * 72 + jn * 16 + g * 4] = wA;
      *(uint2*)&pwB[lr * 72 + jn * 16 + g * 4] = wB;
    }

    // PV: A = P (m=q), B = V^T rows (n=d). Same-wave DS RAW is in-order.
    const bf16x8 pfA0 = *(const bf16x8*)&pw [lr * 72 + kg];
    const bf16x8 pfA1 = *(const bf16x8*)&pw [lr * 72 + 32 + kg];
    const bf16x8 pfB0 = *(const bf16x8*)&pwB[lr * 72 + kg];
    const bf16x8 pfB1 = *(const bf16x8*)&pwB[lr * 72 + 32 + kg];
#pragma unroll
    for (int dn = 0; dn < 4; ++dn) {
      const bf16x8 vf0 = *(const bf16x8*)&Vc[(dn * 16 + lr) * 32 + kg];
      const bf16x8 vf1 = *(const bf16x8*)&Vc[2048 + (dn * 16 + lr) * 32 + kg];
      accA[dn] = __builtin_amdgcn_mfma_f32_16x16x32_bf16(pfA0, vf0, accA[dn], 0, 0, 0);
      accA[dn] = __builtin_amdgcn_mfma_f32_16x16x32_bf16(pfA1, vf1, accA[dn], 0, 0, 0);
      accB[dn] = __builtin_amdgcn_mfma_f32_16x16x32_bf16(pfB0, vf0, accB[dn], 0, 0, 0);
      accB[dn] = __builtin_amdgcn_mfma_f32_16x16x32_bf16(pfB1, vf1, accB[dn], 0, 0, 0);
    }
    cur ^= 1;
  }

  // lsum reductions: lane partial covers key subset for q=lr of each set
  float lA = (lsA0[0] + lsA0[1]) + (lsA1[0] + lsA1[1]);
  lA += __shfl_xor(lA, 16, 64);
  lA += __shfl_xor(lA, 32, 64);
  float lB = (lsB0[0] + lsB0[1]) + (lsB1[0] + lsB1[1]);
  lB += __shfl_xor(lB, 16, 64);
  lB += __shfl_xor(lB, 32, 64);
  Ls[wave * 32 + lr]      = lA;  // same-value multi-write across g, benign
  Ls[wave * 32 + 16 + lr] = lB;
  __syncthreads();

  const int bb = bh >> 4, hh = bh & 15;
#pragma unroll
  for (int r = 0; r < 4; ++r) {
    const int qq = g * 4 + r;
    const float invA = 1.f / fmaxf(Ls[wave * 32 + qq], 1e-30f);
    const float invB = 1.f / fmaxf(Ls[wave * 32 + 16 + qq], 1e-30f);
    const int tiA = q0 + wave * 32 + qq;
    u16* dstA = AO + (((size_t)bb * TSEQ + tiA) * NH + hh) * DH + lr;
    u16* dstB = AO + (((size_t)bb * TSEQ + tiA + 16) * NH + hh) * DH + lr;
#pragma unroll
    for (int dn = 0; dn < 4; ++dn) {
      dstA[dn * 16] = f2bf(accA[dn][r] * invA);
      dstB[dn * 16] = f2bf(accB[dn][r] * invB);
    }
  }
}

// ---------------------------------------------------------------------------
// Kernel 3: output projection  out = AO @ Wo^T + bo  (BK=64 two-buffer).
// ---------------------------------------------------------------------------
__global__ __launch_bounds__(256) void out_gemm(
    const int* __restrict__ flag_p,
    const u16* __restrict__ A, const u16* __restrict__ W,
    const void* __restrict__ bias_raw, void* __restrict__ outp)
{
  __shared__ __align__(16) u16 As[2 * 128 * 32];
  __shared__ __align__(16) u16 Bs[2 * 128 * 32];
  const int flag = *flag_p;
  const int t = threadIdx.x;
  const int m0 = blockIdx.x * 128;
  const int n0 = blockIdx.y * 128;
  const int wave = t >> 6, lane = t & 63;
  const int wm = (wave >> 1) * 64, wn = (wave & 1) * 64;
  const int lr = lane & 15, kg = (lane >> 4) * 8;

  const int srow0 = t >> 2, skc = (t & 3) * 8;
  const int srow1 = srow0 + 64;
  const u16* a0 = A + (size_t)(m0 + srow0) * D_MODEL + skc;
  const u16* a1 = A + (size_t)(m0 + srow1) * D_MODEL + skc;
  const u16* b0 = W + (size_t)(n0 + srow0) * D_MODEL + skc;
  const u16* b1 = W + (size_t)(n0 + srow1) * D_MODEL + skc;

  f32x4 acc[4][4] = {};

  for (int kt = 0; kt < D_MODEL / 64; ++kt) {
    gl_lds16(a0,      &As[t * 8]);
    gl_lds16(a1,      &As[(t + 256) * 8]);
    gl_lds16(a0 + 32, &As[4096 + t * 8]);
    gl_lds16(a1 + 32, &As[4096 + (t + 256) * 8]);
    gl_lds16(b0,      &Bs[t * 8]);
    gl_lds16(b1,      &Bs[(t + 256) * 8]);
    gl_lds16(b0 + 32, &Bs[4096 + t * 8]);
    gl_lds16(b1 + 32, &Bs[4096 + (t + 256) * 8]);
    a0 += 64; a1 += 64; b0 += 64; b1 += 64;
    __syncthreads();
#pragma unroll
    for (int h = 0; h < 2; ++h) {
      bf16x8 af[4], bfr[4];
#pragma unroll
      for (int i = 0; i < 4; ++i)
        af[i] = *(const bf16x8*)&As[h * 4096 + (wm + i * 16 + lr) * 32 + kg];
#pragma unroll
      for (int j = 0; j < 4; ++j)
        bfr[j] = *(const bf16x8*)&Bs[h * 4096 + (wn + j * 16 + lr) * 32 + kg];
#pragma unroll
      for (int i = 0; i < 4; ++i)
#pragma unroll
        for (int j = 0; j < 4; ++j)
          acc[i][j] = __builtin_amdgcn_mfma_f32_16x16x32_bf16(af[i], bfr[j], acc[i][j], 0, 0, 0);
    }
    __syncthreads();
  }

#pragma unroll
  for (int j = 0; j < 4; ++j) {
    const int colg = n0 + wn + j * 16 + lr;
    const float bv = flag ? bf2f(((const u16*)bias_raw)[colg])
                          : ((const float*)bias_raw)[colg];
#pragma unroll
    for (int i = 0; i < 4; ++i) {
      const int rowg = m0 + wm + i * 16 + ((lane >> 4) << 2);
      if (flag) {
        u16* dst = (u16*)outp + (size_t)rowg * D_MODEL + colg;
#pragma unroll
        for (int r = 0; r < 4; ++r)
          dst[(size_t)r * D_MODEL] = f2bf(acc[i][j][r] + bv);
      } else {
        float* dst = (float*)outp + (size_t)rowg * D_MODEL + colg;
#pragma unroll
        for (int r = 0; r < 4; ++r)
          dst[(size_t)r * D_MODEL] = acc[i][j][r] + bv;
      }
    }
  }
}

extern "C" void kernel_launch(void* const* d_in, const int* in_sizes, int n_in,
                              void* d_out, int out_size, void* d_ws, size_t ws_size,
                              hipStream_t stream) {
  const void* x  = d_in[0];
  const void* wq = d_in[1];
  const void* wk = d_in[2];
  const void* wv = d_in[3];
  const void* wo = d_in[4];
  const void* bo = d_in[5];
  u16* dout = (u16*)d_out;

  // ws: [flag 16B][Wq][Wk][Wv][Wo bf16, 2MiB ea][K][VT][AO 16MiB ea]
  int* flag = (int*)d_ws;
  u16* wqb = (u16*)d_ws + 8;
  u16* wkb = wqb + WSZ;
  u16* wvb = wkb + WSZ;
  u16* wob = wvb + WSZ;
  u16* kk  = wob + WSZ;
  u16* vt  = kk + NQ;
  u16* ao  = vt + NQ;

  detect_dtype<<<1, 256, 0, stream>>>((const u32*)wq, flag);

  dim3 gc(NQ / (256 * 8), 5);
  convert_inputs<<<gc, dim3(256), 0, stream>>>(
      x, wq, wk, wv, wo, dout, wqb, wkb, wvb, wob, flag);

  dim3 g1(MTOT / 128, D_MODEL / 128, 3);
  qkv_gemm<<<g1, dim3(256), 0, stream>>>(
      flag, (const u16*)x, dout, wqb, wkb, wvb, kk, vt);

  dim3 g2(BATCH * NH, TSEQ / 128, 1);
  flash_attn<<<g2, dim3(256), 0, stream>>>(flag, dout, kk, vt, ao);

  dim3 g3(MTOT / 128, D_MODEL / 128, 1);
  out_gemm<<<g3, dim3(256), 0, stream>>>(flag, ao, wob, bo, d_out);
}

// Round 3
// 319.924 us; speedup vs baseline: 1.0429x; 1.0429x over previous
//
#include <hip/hip_runtime.h>
#include <stdint.h>

#define D_MODEL 1024
#define NH 16
#define DH 64
#define TSEQ 2048
#define BATCH 4
#define MTOT (BATCH*TSEQ)
#define NQ (MTOT*D_MODEL)      // elements in Q/K/VT/AO and in x
#define WSZ (D_MODEL*D_MODEL)  // elements in each weight matrix
// SCALE * log2(e), pre-folded into Q at the qkv epilogue
#define QSCALE 0.18033688f

typedef __attribute__((ext_vector_type(8))) short bf16x8;
typedef __attribute__((ext_vector_type(8))) unsigned short u16x8;
typedef __attribute__((ext_vector_type(4))) float f32x4;
typedef __attribute__((ext_vector_type(2))) float f32x2;
typedef unsigned short u16;
typedef unsigned int u32;

__device__ __forceinline__ void gl_lds16(const void* g, void* l) {
  __builtin_amdgcn_global_load_lds(
      (__attribute__((address_space(1))) void*)g,
      (__attribute__((address_space(3))) void*)l, 16, 0, 0);
}
__device__ __forceinline__ u16 f2bf(float f) {
  u32 u = __builtin_bit_cast(u32, f);
  u = u + 0x7fffu + ((u >> 16) & 1u);
  return (u16)(u >> 16);
}
__device__ __forceinline__ float bf2f(u16 b) {
  u32 u = ((u32)b) << 16;
  return __builtin_bit_cast(float, u);
}
// packed bf16 convert: lo16 = bf16(lo), hi16 = bf16(hi). One VALU op vs 3.
// NOTE (round-2 lesson): inputs must come from REGULAR VALU producers.
// Feeding a raw v_exp_f32 (TRANS) result directly into this inline asm
// broke correctness in round 2 (absmax 9.6e-3) — keep guarded exp2f.
__device__ __forceinline__ u32 cvtpk(float lo, float hi) {
  u32 r;
  asm("v_cvt_pk_bf16_f32 %0, %1, %2" : "=v"(r) : "v"(lo), "v"(hi));
  return r;
}

// ---------------------------------------------------------------------------
// Kernel 0: input dtype detection (1 = bf16, 0 = fp32). Round-4 verified.
// ---------------------------------------------------------------------------
__global__ __launch_bounds__(256) void detect_dtype(
    const u32* __restrict__ wq_raw, int* __restrict__ flag)
{
  __shared__ int cnt;
  if (threadIdx.x == 0) cnt = 0;
  __syncthreads();
  int c = 0;
  for (int i = threadIdx.x; i < 2048; i += 256) {
    const u32 e = (wq_raw[i] >> 7) & 0xFFu;
    if (e >= 90u && e <= 126u) ++c;
  }
  atomicAdd(&cnt, c);
  __syncthreads();
  if (threadIdx.x == 0) *flag = (cnt > 1024) ? 1 : 0;
}

// ---------------------------------------------------------------------------
// Kernel 0b: convert inputs to bf16. seg 0 = x -> d_out low half (fp32 only),
// 1..4 = Wq,Wk,Wv,Wo -> d_ws.
// ---------------------------------------------------------------------------
__global__ __launch_bounds__(256) void convert_inputs(
    const void* __restrict__ x, const void* __restrict__ wq,
    const void* __restrict__ wk, const void* __restrict__ wv,
    const void* __restrict__ wo,
    u16* __restrict__ xb, u16* __restrict__ wqb, u16* __restrict__ wkb,
    u16* __restrict__ wvb, u16* __restrict__ wob,
    const int* __restrict__ flag_p)
{
  const int flag = *flag_p;
  const int seg = blockIdx.y;
  const void* src; u16* dst; int n;
  switch (seg) {
    case 0:  src = x;  dst = xb;  n = NQ;  break;
    case 1:  src = wq; dst = wqb; n = WSZ; break;
    case 2:  src = wk; dst = wkb; n = WSZ; break;
    case 3:  src = wv; dst = wvb; n = WSZ; break;
    default: src = wo; dst = wob; n = WSZ; break;
  }
  if (flag && seg == 0) return;
  const int idx = (blockIdx.x * 256 + threadIdx.x) * 8;
  if (idx >= n) return;
  if (flag) {
    *(u16x8*)(dst + idx) = *(const u16x8*)((const u16*)src + idx);
  } else {
    const float4 f0 = *(const float4*)((const float*)src + idx);
    const float4 f1 = *(const float4*)((const float*)src + idx + 4);
    union { u16 s[8]; u16x8 v; } u;
    u.s[0] = f2bf(f0.x); u.s[1] = f2bf(f0.y); u.s[2] = f2bf(f0.z); u.s[3] = f2bf(f0.w);
    u.s[4] = f2bf(f1.x); u.s[5] = f2bf(f1.y); u.s[6] = f2bf(f1.z); u.s[7] = f2bf(f1.w);
    *(u16x8*)(dst + idx) = u.v;
  }
}

// ---------------------------------------------------------------------------
// Kernel 1: QKV projection. BK=64 via TWO BK=32 buffers per barrier-pair
// (keeps conflict-free 32-col layout + gl_lds contiguity; 32 KB LDS).
// z=0 -> Q^T [B,H,64,T] (pre-scaled); z=1 -> K [B,H,T,64]; z=2 -> V^T.
// ---------------------------------------------------------------------------
__global__ __launch_bounds__(256) void qkv_gemm(
    const int* __restrict__ flag_p, const u16* __restrict__ x_raw,
    u16* __restrict__ dout,
    const u16* __restrict__ Wq, const u16* __restrict__ Wk,
    const u16* __restrict__ Wv,
    u16* __restrict__ Ko, u16* __restrict__ VTo)
{
  __shared__ __align__(16) u16 As[2 * 128 * 32];
  __shared__ __align__(16) u16 Bs[2 * 128 * 32];
  const int flag = *flag_p;
  const u16* __restrict__ X = flag ? x_raw : dout;  // converted x in dout low
  u16* __restrict__ QTo = flag ? dout : dout + NQ;
  const int t = threadIdx.x;
  const int z = blockIdx.z;
  const u16* __restrict__ W = (z == 0) ? Wq : (z == 1) ? Wk : Wv;
  const int m0 = blockIdx.x * 128;
  const int n0 = blockIdx.y * 128;
  const int wave = t >> 6, lane = t & 63;
  const int wm = (wave >> 1) * 64, wn = (wave & 1) * 64;
  const int lr = lane & 15, kg = (lane >> 4) * 8;

  const int srow0 = t >> 2, skc = (t & 3) * 8;
  const int srow1 = srow0 + 64;
  const u16* a0 = X + (size_t)(m0 + srow0) * D_MODEL + skc;
  const u16* a1 = X + (size_t)(m0 + srow1) * D_MODEL + skc;
  const u16* b0 = W + (size_t)(n0 + srow0) * D_MODEL + skc;
  const u16* b1 = W + (size_t)(n0 + srow1) * D_MODEL + skc;

  f32x4 acc[4][4] = {};

  for (int kt = 0; kt < D_MODEL / 64; ++kt) {
    gl_lds16(a0,      &As[t * 8]);
    gl_lds16(a1,      &As[(t + 256) * 8]);
    gl_lds16(a0 + 32, &As[4096 + t * 8]);
    gl_lds16(a1 + 32, &As[4096 + (t + 256) * 8]);
    gl_lds16(b0,      &Bs[t * 8]);
    gl_lds16(b1,      &Bs[(t + 256) * 8]);
    gl_lds16(b0 + 32, &Bs[4096 + t * 8]);
    gl_lds16(b1 + 32, &Bs[4096 + (t + 256) * 8]);
    a0 += 64; a1 += 64; b0 += 64; b1 += 64;
    __syncthreads();
#pragma unroll
    for (int h = 0; h < 2; ++h) {
      bf16x8 af[4], bfr[4];
#pragma unroll
      for (int i = 0; i < 4; ++i)
        af[i] = *(const bf16x8*)&As[h * 4096 + (wm + i * 16 + lr) * 32 + kg];
#pragma unroll
      for (int j = 0; j < 4; ++j)
        bfr[j] = *(const bf16x8*)&Bs[h * 4096 + (wn + j * 16 + lr) * 32 + kg];
#pragma unroll
      for (int i = 0; i < 4; ++i)
#pragma unroll
        for (int j = 0; j < 4; ++j)
          acc[i][j] = __builtin_amdgcn_mfma_f32_16x16x32_bf16(af[i], bfr[j], acc[i][j], 0, 0, 0);
    }
    __syncthreads();
  }

  // C/D layout: col = lane&15, row = (lane>>4)*4 + reg
  const int bidx = m0 >> 11;
  if (z == 1) {
    // K: [B,H,T,64], scalar stores (d-contiguous rows for flash staging)
#pragma unroll
    for (int i = 0; i < 4; ++i) {
      const int rowg = m0 + wm + i * 16 + ((lane >> 4) << 2);
      const int tq = rowg & (TSEQ - 1);
#pragma unroll
      for (int j = 0; j < 4; ++j) {
        const int colg = n0 + wn + j * 16 + lr;
        const int h = colg >> 6, d = colg & 63;
        u16* dst = Ko + ((size_t)(bidx * NH + h) * TSEQ + tq) * DH + d;
#pragma unroll
        for (int r = 0; r < 4; ++r)
          dst[(size_t)r * DH] = f2bf(acc[i][j][r]);
      }
    }
  } else {
    // Q^T (scaled) and V^T: [B,H,64,T], vectorized 8B stores along t
    u16* O = (z == 0) ? QTo : VTo;
    const float sc = (z == 0) ? QSCALE : 1.0f;
#pragma unroll
    for (int i = 0; i < 4; ++i) {
      const int rowg = m0 + wm + i * 16 + ((lane >> 4) << 2);
      const int tq = rowg & (TSEQ - 1);  // multiple of 4 -> 8B aligned
#pragma unroll
      for (int j = 0; j < 4; ++j) {
        const int colg = n0 + wn + j * 16 + lr;
        const int h = colg >> 6, d = colg & 63;
        union { u16 s[4]; uint2 v; } u;
#pragma unroll
        for (int r = 0; r < 4; ++r) u.s[r] = f2bf(acc[i][j][r] * sc);
        *(uint2*)&O[((size_t)(bidx * NH + h) * DH + d) * TSEQ + tq] = u.v;
      }
    }
  }
}

// ---------------------------------------------------------------------------
// Kernel 2: flash attention. ROUND-3: round-2's 64 q-rows per wave (4 q-sets,
// 256 q/block) with the raw-exp change REVERTED (guarded __builtin_exp2f) —
// round 2's correctness failure isolated to the raw-TRANS-into-inline-asm exp.
// Each K/V LDS fragment feeds 4 MFMA: K/V ds_read traffic and barrier count
// per FLOP halve vs round 1. Double-buffered K/V staging, 1 barrier/tile.
// Grid = (64 bh, 8 qblk) = 512 blocks = 2 blocks/CU; LDS 69 KB -> 2/CU.
// XCD-locality: linear id % 8 == bh % 8 -> all 8 q-blocks of one (b,h)
// share an XCD; its K/V slice (512 KB) L2-resident, 8 slices = 4 MiB = L2.
// ---------------------------------------------------------------------------
__global__ __launch_bounds__(256) void flash_attn(
    const int* __restrict__ flag_p, const u16* __restrict__ dout,
    const u16* __restrict__ K, const u16* __restrict__ VT,
    u16* __restrict__ AO)
{
  __shared__ __align__(16) u16 Ks[2][2 * 64 * 32];  // [buf][half][64 keys][32 d]
  __shared__ __align__(16) u16 Vs[2][2 * 64 * 32];  // [buf][half][64 d][32 keys]
  __shared__ __align__(16) u16 Ps[4 * 64 * 72];     // per-wave [64 q][64+8 keys]
  __shared__ float Ls[4 * 64];
  const int flag = *flag_p;
  const u16* __restrict__ QT = flag ? dout : dout + NQ;
  const int t = threadIdx.x;
  const int wave = t >> 6, lane = t & 63;
  const int lr = lane & 15, g = lane >> 4, kg = g * 8;
  const int bh = blockIdx.x;          // fastest grid dim -> XCD = bh % 8
  const int q0 = blockIdx.y * 256;
  const u16* __restrict__ QTh = QT + (size_t)bh * DH * TSEQ;  // [64 d][T]
  const u16* __restrict__ Kh = K + (size_t)bh * TSEQ * DH;
  const u16* __restrict__ Vh = VT + (size_t)bh * DH * TSEQ;

  // 8 Q B-fragments per wave: q-sets s=0..3 (16 q each), d-halves 0/1.
  // Gathered from Q^T once per kernel: 64 strided scalar loads.
  const int qi = q0 + wave * 64 + lr;
  bf16x8 qf[8];
#pragma unroll
  for (int s = 0; s < 4; ++s) {
    union { u16 v[8]; bf16x8 b; } u0, u1;
#pragma unroll
    for (int j = 0; j < 8; ++j) {
      u0.v[j] = QTh[(size_t)(kg + j) * TSEQ + qi + s * 16];
      u1.v[j] = QTh[(size_t)(32 + kg + j) * TSEQ + qi + s * 16];
    }
    qf[s * 2] = u0.b; qf[s * 2 + 1] = u1.b;
  }

  f32x4 acc[4][4] = {};                 // [set][dn]
  f32x2 ls0[4] = {}, ls1[4] = {};

  const int srow = t >> 2, skc = (t & 3) * 8;
  const u16* kb = Kh + (size_t)srow * DH + skc;
  const u16* vb = Vh + (size_t)srow * TSEQ + skc;
  u16* const pw = &Ps[wave * 64 * 72];  // q-set s at rows s*16..s*16+15

  // prologue: prefetch tile 0 into buffer 0
  gl_lds16(kb,      &Ks[0][t * 8]);          // keys, d 0..31
  gl_lds16(kb + 32, &Ks[0][(t + 256) * 8]);  // keys, d 32..63
  gl_lds16(vb,      &Vs[0][t * 8]);          // [d][keys 0..31]
  gl_lds16(vb + 32, &Vs[0][(t + 256) * 8]);  // [d][keys 32..63]
  kb += 64 * DH; vb += 64;

  int cur = 0;
  for (int j0 = 0; j0 < TSEQ; j0 += 64) {
    // single barrier per tile: drains cur-buf loads (issued a full tile ago)
    // and guarantees everyone is done reading buf^1 before we overwrite it.
    __syncthreads();
    if (j0 + 64 < TSEQ) {
      gl_lds16(kb,      &Ks[cur ^ 1][t * 8]);
      gl_lds16(kb + 32, &Ks[cur ^ 1][(t + 256) * 8]);
      gl_lds16(vb,      &Vs[cur ^ 1][t * 8]);
      gl_lds16(vb + 32, &Vs[cur ^ 1][(t + 256) * 8]);
      kb += 64 * DH; vb += 64;
    }
    const u16* __restrict__ Kc = Ks[cur];
    const u16* __restrict__ Vc = Vs[cur];

    // S^T tiles: C col = q (lr), row = key = jn*16 + g*4 + r
#pragma unroll
    for (int jn = 0; jn < 4; ++jn) {
      const bf16x8 kf0 = *(const bf16x8*)&Kc[(jn * 16 + lr) * 32 + kg];
      const bf16x8 kf1 = *(const bf16x8*)&Kc[2048 + (jn * 16 + lr) * 32 + kg];
#pragma unroll
      for (int s = 0; s < 4; ++s) {
        f32x4 sS = {};
        sS = __builtin_amdgcn_mfma_f32_16x16x32_bf16(kf0, qf[s * 2],     sS, 0, 0, 0);
        sS = __builtin_amdgcn_mfma_f32_16x16x32_bf16(kf1, qf[s * 2 + 1], sS, 0, 0, 0);
        const float e0 = __builtin_exp2f(sS[0]);
        const float e1 = __builtin_exp2f(sS[1]);
        const float e2 = __builtin_exp2f(sS[2]);
        const float e3 = __builtin_exp2f(sS[3]);
        ls0[s] += (f32x2){e0, e1};
        ls1[s] += (f32x2){e2, e3};
        uint2 w;
        w.x = cvtpk(e0, e1); w.y = cvtpk(e2, e3);
        *(uint2*)&pw[s * 16 * 72 + lr * 72 + jn * 16 + g * 4] = w;
      }
    }

    // PV: A = P (m=q), B = V^T rows (n=d). Same-wave DS RAW is in-order.
    bf16x8 pf0[4], pf1[4];
#pragma unroll
    for (int s = 0; s < 4; ++s) {
      pf0[s] = *(const bf16x8*)&pw[s * 16 * 72 + lr * 72 + kg];
      pf1[s] = *(const bf16x8*)&pw[s * 16 * 72 + lr * 72 + 32 + kg];
    }
#pragma unroll
    for (int dn = 0; dn < 4; ++dn) {
      const bf16x8 vf0 = *(const bf16x8*)&Vc[(dn * 16 + lr) * 32 + kg];
      const bf16x8 vf1 = *(const bf16x8*)&Vc[2048 + (dn * 16 + lr) * 32 + kg];
#pragma unroll
      for (int s = 0; s < 4; ++s) {
        acc[s][dn] = __builtin_amdgcn_mfma_f32_16x16x32_bf16(pf0[s], vf0, acc[s][dn], 0, 0, 0);
        acc[s][dn] = __builtin_amdgcn_mfma_f32_16x16x32_bf16(pf1[s], vf1, acc[s][dn], 0, 0, 0);
      }
    }
    cur ^= 1;
  }

  // lsum reductions: lane partial covers key subset for q=lr of each set.
  // Ls rows are wave-private; same-value multi-write across g is benign.
#pragma unroll
  for (int s = 0; s < 4; ++s) {
    float l = (ls0[s][0] + ls0[s][1]) + (ls1[s][0] + ls1[s][1]);
    l += __shfl_xor(l, 16, 64);
    l += __shfl_xor(l, 32, 64);
    Ls[wave * 64 + s * 16 + lr] = l;
  }
  __syncthreads();

  const int bb = bh >> 4, hh = bh & 15;
#pragma unroll
  for (int s = 0; s < 4; ++s) {
#pragma unroll
    for (int r = 0; r < 4; ++r) {
      const int qq = g * 4 + r;
      const float inv = 1.f / fmaxf(Ls[wave * 64 + s * 16 + qq], 1e-30f);
      const int ti = q0 + wave * 64 + s * 16 + qq;
      u16* dst = AO + (((size_t)bb * TSEQ + ti) * NH + hh) * DH + lr;
#pragma unroll
      for (int dn = 0; dn < 4; ++dn)
        dst[dn * 16] = f2bf(acc[s][dn][r] * inv);
    }
  }
}

// ---------------------------------------------------------------------------
// Kernel 3: output projection  out = AO @ Wo^T + bo  (BK=64 two-buffer).
// ---------------------------------------------------------------------------
__global__ __launch_bounds__(256) void out_gemm(
    const int* __restrict__ flag_p,
    const u16* __restrict__ A, const u16* __restrict__ W,
    const void* __restrict__ bias_raw, void* __restrict__ outp)
{
  __shared__ __align__(16) u16 As[2 * 128 * 32];
  __shared__ __align__(16) u16 Bs[2 * 128 * 32];
  const int flag = *flag_p;
  const int t = threadIdx.x;
  const int m0 = blockIdx.x * 128;
  const int n0 = blockIdx.y * 128;
  const int wave = t >> 6, lane = t & 63;
  const int wm = (wave >> 1) * 64, wn = (wave & 1) * 64;
  const int lr = lane & 15, kg = (lane >> 4) * 8;

  const int srow0 = t >> 2, skc = (t & 3) * 8;
  const int srow1 = srow0 + 64;
  const u16* a0 = A + (size_t)(m0 + srow0) * D_MODEL + skc;
  const u16* a1 = A + (size_t)(m0 + srow1) * D_MODEL + skc;
  const u16* b0 = W + (size_t)(n0 + srow0) * D_MODEL + skc;
  const u16* b1 = W + (size_t)(n0 + srow1) * D_MODEL + skc;

  f32x4 acc[4][4] = {};

  for (int kt = 0; kt < D_MODEL / 64; ++kt) {
    gl_lds16(a0,      &As[t * 8]);
    gl_lds16(a1,      &As[(t + 256) * 8]);
    gl_lds16(a0 + 32, &As[4096 + t * 8]);
    gl_lds16(a1 + 32, &As[4096 + (t + 256) * 8]);
    gl_lds16(b0,      &Bs[t * 8]);
    gl_lds16(b1,      &Bs[(t + 256) * 8]);
    gl_lds16(b0 + 32, &Bs[4096 + t * 8]);
    gl_lds16(b1 + 32, &Bs[4096 + (t + 256) * 8]);
    a0 += 64; a1 += 64; b0 += 64; b1 += 64;
    __syncthreads();
#pragma unroll
    for (int h = 0; h < 2; ++h) {
      bf16x8 af[4], bfr[4];
#pragma unroll
      for (int i = 0; i < 4; ++i)
        af[i] = *(const bf16x8*)&As[h * 4096 + (wm + i * 16 + lr) * 32 + kg];
#pragma unroll
      for (int j = 0; j < 4; ++j)
        bfr[j] = *(const bf16x8*)&Bs[h * 4096 + (wn + j * 16 + lr) * 32 + kg];
#pragma unroll
      for (int i = 0; i < 4; ++i)
#pragma unroll
        for (int j = 0; j < 4; ++j)
          acc[i][j] = __builtin_amdgcn_mfma_f32_16x16x32_bf16(af[i], bfr[j], acc[i][j], 0, 0, 0);
    }
    __syncthreads();
  }

#pragma unroll
  for (int j = 0; j < 4; ++j) {
    const int colg = n0 + wn + j * 16 + lr;
    const float bv = flag ? bf2f(((const u16*)bias_raw)[colg])
                          : ((const float*)bias_raw)[colg];
#pragma unroll
    for (int i = 0; i < 4; ++i) {
      const int rowg = m0 + wm + i * 16 + ((lane >> 4) << 2);
      if (flag) {
        u16* dst = (u16*)outp + (size_t)rowg * D_MODEL + colg;
#pragma unroll
        for (int r = 0; r < 4; ++r)
          dst[(size_t)r * D_MODEL] = f2bf(acc[i][j][r] + bv);
      } else {
        float* dst = (float*)outp + (size_t)rowg * D_MODEL + colg;
#pragma unroll
        for (int r = 0; r < 4; ++r)
          dst[(size_t)r * D_MODEL] = acc[i][j][r] + bv;
      }
    }
  }
}

extern "C" void kernel_launch(void* const* d_in, const int* in_sizes, int n_in,
                              void* d_out, int out_size, void* d_ws, size_t ws_size,
                              hipStream_t stream) {
  const void* x  = d_in[0];
  const void* wq = d_in[1];
  const void* wk = d_in[2];
  const void* wv = d_in[3];
  const void* wo = d_in[4];
  const void* bo = d_in[5];
  u16* dout = (u16*)d_out;

  // ws: [flag 16B][Wq][Wk][Wv][Wo bf16, 2MiB ea][K][VT][AO 16MiB ea]
  int* flag = (int*)d_ws;
  u16* wqb = (u16*)d_ws + 8;
  u16* wkb = wqb + WSZ;
  u16* wvb = wkb + WSZ;
  u16* wob = wvb + WSZ;
  u16* kk  = wob + WSZ;
  u16* vt  = kk + NQ;
  u16* ao  = vt + NQ;

  detect_dtype<<<1, 256, 0, stream>>>((const u32*)wq, flag);

  dim3 gc(NQ / (256 * 8), 5);
  convert_inputs<<<gc, dim3(256), 0, stream>>>(
      x, wq, wk, wv, wo, dout, wqb, wkb, wvb, wob, flag);

  dim3 g1(MTOT / 128, D_MODEL / 128, 3);
  qkv_gemm<<<g1, dim3(256), 0, stream>>>(
      flag, (const u16*)x, dout, wqb, wkb, wvb, kk, vt);

  dim3 g2(BATCH * NH, TSEQ / 256, 1);
  flash_attn<<<g2, dim3(256), 0, stream>>>(flag, dout, kk, vt, ao);

  dim3 g3(MTOT / 128, D_MODEL / 128, 1);
  out_gemm<<<g3, dim3(256), 0, stream>>>(flag, ao, wob, bo, d_out);
}

// Round 4
// 290.082 us; speedup vs baseline: 1.1502x; 1.1029x over previous
//
#include <hip/hip_runtime.h>
#include <stdint.h>

#define D_MODEL 1024
#define NH 16
#define DH 64
#define TSEQ 2048
#define BATCH 4
#define MTOT (BATCH*TSEQ)
#define NQ (MTOT*D_MODEL)      // elements in Q/K/VT/AO and in x
#define WSZ (D_MODEL*D_MODEL)  // elements in each weight matrix
// SCALE * log2(e), pre-folded into Q at the qkv epilogue
#define QSCALE 0.18033688f

typedef __attribute__((ext_vector_type(8))) short bf16x8;
typedef __attribute__((ext_vector_type(8))) unsigned short u16x8;
typedef __attribute__((ext_vector_type(4))) float f32x4;
typedef __attribute__((ext_vector_type(2))) float f32x2;
typedef unsigned short u16;
typedef unsigned int u32;

__device__ __forceinline__ void gl_lds16(const void* g, void* l) {
  __builtin_amdgcn_global_load_lds(
      (__attribute__((address_space(1))) void*)g,
      (__attribute__((address_space(3))) void*)l, 16, 0, 0);
}
__device__ __forceinline__ u16 f2bf(float f) {
  u32 u = __builtin_bit_cast(u32, f);
  u = u + 0x7fffu + ((u >> 16) & 1u);
  return (u16)(u >> 16);
}
__device__ __forceinline__ float bf2f(u16 b) {
  u32 u = ((u32)b) << 16;
  return __builtin_bit_cast(float, u);
}

// ---------------------------------------------------------------------------
// Fused raw exp2 + bf16 pack, hazards controlled IN-ASM.
// Round-2 lesson: v_exp_f32 (TRANS) results consumed by a SEPARATE inline-asm
// v_cvt_pk within the hazard window gave wrong numerics (absmax 9.6e-3) —
// the post-RA hazard recognizer doesn't insert TRANS-use waits for INLINEASM
// consumers. The guarded __builtin_exp2f also ends in v_exp_f32, so for
// in-range inputs semantics are identical; only scheduling differed.
// Fix: one asm block, 4 independent exps back-to-back (>=3 instr spacing for
// the packs) + s_nop 1 before the packs; float outputs escape with the two
// packs as spacing for compiler-side consumers.
// ---------------------------------------------------------------------------
__device__ __forceinline__ void exp2pk4(const f32x4 s, float& e0, float& e1,
                                        float& e2, float& e3, u32& pk01,
                                        u32& pk23) {
  asm("v_exp_f32 %0, %6\n\t"
      "v_exp_f32 %1, %7\n\t"
      "v_exp_f32 %2, %8\n\t"
      "v_exp_f32 %3, %9\n\t"
      "s_nop 1\n\t"
      "v_cvt_pk_bf16_f32 %4, %0, %1\n\t"
      "v_cvt_pk_bf16_f32 %5, %2, %3"
      : "=&v"(e0), "=&v"(e1), "=&v"(e2), "=&v"(e3), "=&v"(pk01), "=&v"(pk23)
      : "v"(s[0]), "v"(s[1]), "v"(s[2]), "v"(s[3]));
}

// ---------------------------------------------------------------------------
// Kernel 0: input dtype detection (1 = bf16, 0 = fp32). Round-4 verified.
// ---------------------------------------------------------------------------
__global__ __launch_bounds__(256) void detect_dtype(
    const u32* __restrict__ wq_raw, int* __restrict__ flag)
{
  __shared__ int cnt;
  if (threadIdx.x == 0) cnt = 0;
  __syncthreads();
  int c = 0;
  for (int i = threadIdx.x; i < 2048; i += 256) {
    const u32 e = (wq_raw[i] >> 7) & 0xFFu;
    if (e >= 90u && e <= 126u) ++c;
  }
  atomicAdd(&cnt, c);
  __syncthreads();
  if (threadIdx.x == 0) *flag = (cnt > 1024) ? 1 : 0;
}

// ---------------------------------------------------------------------------
// Kernel 0b: convert inputs to bf16. seg 0 = x -> d_out low half (fp32 only),
// 1..4 = Wq,Wk,Wv,Wo -> d_ws.
// ---------------------------------------------------------------------------
__global__ __launch_bounds__(256) void convert_inputs(
    const void* __restrict__ x, const void* __restrict__ wq,
    const void* __restrict__ wk, const void* __restrict__ wv,
    const void* __restrict__ wo,
    u16* __restrict__ xb, u16* __restrict__ wqb, u16* __restrict__ wkb,
    u16* __restrict__ wvb, u16* __restrict__ wob,
    const int* __restrict__ flag_p)
{
  const int flag = *flag_p;
  const int seg = blockIdx.y;
  const void* src; u16* dst; int n;
  switch (seg) {
    case 0:  src = x;  dst = xb;  n = NQ;  break;
    case 1:  src = wq; dst = wqb; n = WSZ; break;
    case 2:  src = wk; dst = wkb; n = WSZ; break;
    case 3:  src = wv; dst = wvb; n = WSZ; break;
    default: src = wo; dst = wob; n = WSZ; break;
  }
  if (flag && seg == 0) return;
  const int idx = (blockIdx.x * 256 + threadIdx.x) * 8;
  if (idx >= n) return;
  if (flag) {
    *(u16x8*)(dst + idx) = *(const u16x8*)((const u16*)src + idx);
  } else {
    const float4 f0 = *(const float4*)((const float*)src + idx);
    const float4 f1 = *(const float4*)((const float*)src + idx + 4);
    union { u16 s[8]; u16x8 v; } u;
    u.s[0] = f2bf(f0.x); u.s[1] = f2bf(f0.y); u.s[2] = f2bf(f0.z); u.s[3] = f2bf(f0.w);
    u.s[4] = f2bf(f1.x); u.s[5] = f2bf(f1.y); u.s[6] = f2bf(f1.z); u.s[7] = f2bf(f1.w);
    *(u16x8*)(dst + idx) = u.v;
  }
}

// ---------------------------------------------------------------------------
// Kernel 1: QKV projection. BK=64 via TWO BK=32 buffers per barrier-pair
// (keeps conflict-free 32-col layout + gl_lds contiguity; 32 KB LDS).
// z=0 -> Q^T [B,H,64,T] (pre-scaled); z=1 -> K [B,H,T,64]; z=2 -> V^T.
// ---------------------------------------------------------------------------
__global__ __launch_bounds__(256) void qkv_gemm(
    const int* __restrict__ flag_p, const u16* __restrict__ x_raw,
    u16* __restrict__ dout,
    const u16* __restrict__ Wq, const u16* __restrict__ Wk,
    const u16* __restrict__ Wv,
    u16* __restrict__ Ko, u16* __restrict__ VTo)
{
  __shared__ __align__(16) u16 As[2 * 128 * 32];
  __shared__ __align__(16) u16 Bs[2 * 128 * 32];
  const int flag = *flag_p;
  const u16* __restrict__ X = flag ? x_raw : dout;  // converted x in dout low
  u16* __restrict__ QTo = flag ? dout : dout + NQ;
  const int t = threadIdx.x;
  const int z = blockIdx.z;
  const u16* __restrict__ W = (z == 0) ? Wq : (z == 1) ? Wk : Wv;
  const int m0 = blockIdx.x * 128;
  const int n0 = blockIdx.y * 128;
  const int wave = t >> 6, lane = t & 63;
  const int wm = (wave >> 1) * 64, wn = (wave & 1) * 64;
  const int lr = lane & 15, kg = (lane >> 4) * 8;

  const int srow0 = t >> 2, skc = (t & 3) * 8;
  const int srow1 = srow0 + 64;
  const u16* a0 = X + (size_t)(m0 + srow0) * D_MODEL + skc;
  const u16* a1 = X + (size_t)(m0 + srow1) * D_MODEL + skc;
  const u16* b0 = W + (size_t)(n0 + srow0) * D_MODEL + skc;
  const u16* b1 = W + (size_t)(n0 + srow1) * D_MODEL + skc;

  f32x4 acc[4][4] = {};

  for (int kt = 0; kt < D_MODEL / 64; ++kt) {
    gl_lds16(a0,      &As[t * 8]);
    gl_lds16(a1,      &As[(t + 256) * 8]);
    gl_lds16(a0 + 32, &As[4096 + t * 8]);
    gl_lds16(a1 + 32, &As[4096 + (t + 256) * 8]);
    gl_lds16(b0,      &Bs[t * 8]);
    gl_lds16(b1,      &Bs[(t + 256) * 8]);
    gl_lds16(b0 + 32, &Bs[4096 + t * 8]);
    gl_lds16(b1 + 32, &Bs[4096 + (t + 256) * 8]);
    a0 += 64; a1 += 64; b0 += 64; b1 += 64;
    __syncthreads();
#pragma unroll
    for (int h = 0; h < 2; ++h) {
      bf16x8 af[4], bfr[4];
#pragma unroll
      for (int i = 0; i < 4; ++i)
        af[i] = *(const bf16x8*)&As[h * 4096 + (wm + i * 16 + lr) * 32 + kg];
#pragma unroll
      for (int j = 0; j < 4; ++j)
        bfr[j] = *(const bf16x8*)&Bs[h * 4096 + (wn + j * 16 + lr) * 32 + kg];
#pragma unroll
      for (int i = 0; i < 4; ++i)
#pragma unroll
        for (int j = 0; j < 4; ++j)
          acc[i][j] = __builtin_amdgcn_mfma_f32_16x16x32_bf16(af[i], bfr[j], acc[i][j], 0, 0, 0);
    }
    __syncthreads();
  }

  // C/D layout: col = lane&15, row = (lane>>4)*4 + reg
  const int bidx = m0 >> 11;
  if (z == 1) {
    // K: [B,H,T,64], scalar stores (d-contiguous rows for flash staging)
#pragma unroll
    for (int i = 0; i < 4; ++i) {
      const int rowg = m0 + wm + i * 16 + ((lane >> 4) << 2);
      const int tq = rowg & (TSEQ - 1);
#pragma unroll
      for (int j = 0; j < 4; ++j) {
        const int colg = n0 + wn + j * 16 + lr;
        const int h = colg >> 6, d = colg & 63;
        u16* dst = Ko + ((size_t)(bidx * NH + h) * TSEQ + tq) * DH + d;
#pragma unroll
        for (int r = 0; r < 4; ++r)
          dst[(size_t)r * DH] = f2bf(acc[i][j][r]);
      }
    }
  } else {
    // Q^T (scaled) and V^T: [B,H,64,T], vectorized 8B stores along t
    u16* O = (z == 0) ? QTo : VTo;
    const float sc = (z == 0) ? QSCALE : 1.0f;
#pragma unroll
    for (int i = 0; i < 4; ++i) {
      const int rowg = m0 + wm + i * 16 + ((lane >> 4) << 2);
      const int tq = rowg & (TSEQ - 1);  // multiple of 4 -> 8B aligned
#pragma unroll
      for (int j = 0; j < 4; ++j) {
        const int colg = n0 + wn + j * 16 + lr;
        const int h = colg >> 6, d = colg & 63;
        union { u16 s[4]; uint2 v; } u;
#pragma unroll
        for (int r = 0; r < 4; ++r) u.s[r] = f2bf(acc[i][j][r] * sc);
        *(uint2*)&O[((size_t)(bidx * NH + h) * DH + d) * TSEQ + tq] = u.v;
      }
    }
  }
}

// ---------------------------------------------------------------------------
// Kernel 2: flash attention. 64 q-rows per wave (4 q-sets), 256 q per block;
// each K/V LDS fragment feeds 4 MFMA. Double-buffered K/V staging, 1 barrier
// per tile. ROUND-4: softmax exp via fused in-asm raw v_exp_f32 + cvt_pk
// (exp2pk4) — drops the ~5-op guard arithmetic of __builtin_exp2f while
// controlling the TRANS-use hazard that broke round 2.
// Grid = (64 bh, 8 qblk) = 512 blocks = 2 blocks/CU; LDS 69 KB -> 2/CU.
// XCD-locality: linear id % 8 == bh % 8 -> all 8 q-blocks of one (b,h)
// share an XCD; its K/V slice (512 KB) L2-resident, 8 slices = 4 MiB = L2.
// ---------------------------------------------------------------------------
__global__ __launch_bounds__(256) void flash_attn(
    const int* __restrict__ flag_p, const u16* __restrict__ dout,
    const u16* __restrict__ K, const u16* __restrict__ VT,
    u16* __restrict__ AO)
{
  __shared__ __align__(16) u16 Ks[2][2 * 64 * 32];  // [buf][half][64 keys][32 d]
  __shared__ __align__(16) u16 Vs[2][2 * 64 * 32];  // [buf][half][64 d][32 keys]
  __shared__ __align__(16) u16 Ps[4 * 64 * 72];     // per-wave [64 q][64+8 keys]
  __shared__ float Ls[4 * 64];
  const int flag = *flag_p;
  const u16* __restrict__ QT = flag ? dout : dout + NQ;
  const int t = threadIdx.x;
  const int wave = t >> 6, lane = t & 63;
  const int lr = lane & 15, g = lane >> 4, kg = g * 8;
  const int bh = blockIdx.x;          // fastest grid dim -> XCD = bh % 8
  const int q0 = blockIdx.y * 256;
  const u16* __restrict__ QTh = QT + (size_t)bh * DH * TSEQ;  // [64 d][T]
  const u16* __restrict__ Kh = K + (size_t)bh * TSEQ * DH;
  const u16* __restrict__ Vh = VT + (size_t)bh * DH * TSEQ;

  // 8 Q B-fragments per wave: q-sets s=0..3 (16 q each), d-halves 0/1.
  // Gathered from Q^T once per kernel: 64 strided scalar loads.
  const int qi = q0 + wave * 64 + lr;
  bf16x8 qf[8];
#pragma unroll
  for (int s = 0; s < 4; ++s) {
    union { u16 v[8]; bf16x8 b; } u0, u1;
#pragma unroll
    for (int j = 0; j < 8; ++j) {
      u0.v[j] = QTh[(size_t)(kg + j) * TSEQ + qi + s * 16];
      u1.v[j] = QTh[(size_t)(32 + kg + j) * TSEQ + qi + s * 16];
    }
    qf[s * 2] = u0.b; qf[s * 2 + 1] = u1.b;
  }

  f32x4 acc[4][4] = {};                 // [set][dn]
  f32x2 ls0[4] = {}, ls1[4] = {};

  const int srow = t >> 2, skc = (t & 3) * 8;
  const u16* kb = Kh + (size_t)srow * DH + skc;
  const u16* vb = Vh + (size_t)srow * TSEQ + skc;
  u16* const pw = &Ps[wave * 64 * 72];  // q-set s at rows s*16..s*16+15

  // prologue: prefetch tile 0 into buffer 0
  gl_lds16(kb,      &Ks[0][t * 8]);          // keys, d 0..31
  gl_lds16(kb + 32, &Ks[0][(t + 256) * 8]);  // keys, d 32..63
  gl_lds16(vb,      &Vs[0][t * 8]);          // [d][keys 0..31]
  gl_lds16(vb + 32, &Vs[0][(t + 256) * 8]);  // [d][keys 32..63]
  kb += 64 * DH; vb += 64;

  int cur = 0;
  for (int j0 = 0; j0 < TSEQ; j0 += 64) {
    // single barrier per tile: drains cur-buf loads (issued a full tile ago)
    // and guarantees everyone is done reading buf^1 before we overwrite it.
    __syncthreads();
    if (j0 + 64 < TSEQ) {
      gl_lds16(kb,      &Ks[cur ^ 1][t * 8]);
      gl_lds16(kb + 32, &Ks[cur ^ 1][(t + 256) * 8]);
      gl_lds16(vb,      &Vs[cur ^ 1][t * 8]);
      gl_lds16(vb + 32, &Vs[cur ^ 1][(t + 256) * 8]);
      kb += 64 * DH; vb += 64;
    }
    const u16* __restrict__ Kc = Ks[cur];
    const u16* __restrict__ Vc = Vs[cur];

    // S^T tiles: C col = q (lr), row = key = jn*16 + g*4 + r
#pragma unroll
    for (int jn = 0; jn < 4; ++jn) {
      const bf16x8 kf0 = *(const bf16x8*)&Kc[(jn * 16 + lr) * 32 + kg];
      const bf16x8 kf1 = *(const bf16x8*)&Kc[2048 + (jn * 16 + lr) * 32 + kg];
#pragma unroll
      for (int s = 0; s < 4; ++s) {
        f32x4 sS = {};
        sS = __builtin_amdgcn_mfma_f32_16x16x32_bf16(kf0, qf[s * 2],     sS, 0, 0, 0);
        sS = __builtin_amdgcn_mfma_f32_16x16x32_bf16(kf1, qf[s * 2 + 1], sS, 0, 0, 0);
        float e0, e1, e2, e3;
        uint2 w;
        exp2pk4(sS, e0, e1, e2, e3, w.x, w.y);
        ls0[s] += (f32x2){e0, e1};
        ls1[s] += (f32x2){e2, e3};
        *(uint2*)&pw[s * 16 * 72 + lr * 72 + jn * 16 + g * 4] = w;
      }
    }

    // PV: A = P (m=q), B = V^T rows (n=d). Same-wave DS RAW is in-order.
    bf16x8 pf0[4], pf1[4];
#pragma unroll
    for (int s = 0; s < 4; ++s) {
      pf0[s] = *(const bf16x8*)&pw[s * 16 * 72 + lr * 72 + kg];
      pf1[s] = *(const bf16x8*)&pw[s * 16 * 72 + lr * 72 + 32 + kg];
    }
#pragma unroll
    for (int dn = 0; dn < 4; ++dn) {
      const bf16x8 vf0 = *(const bf16x8*)&Vc[(dn * 16 + lr) * 32 + kg];
      const bf16x8 vf1 = *(const bf16x8*)&Vc[2048 + (dn * 16 + lr) * 32 + kg];
#pragma unroll
      for (int s = 0; s < 4; ++s) {
        acc[s][dn] = __builtin_amdgcn_mfma_f32_16x16x32_bf16(pf0[s], vf0, acc[s][dn], 0, 0, 0);
        acc[s][dn] = __builtin_amdgcn_mfma_f32_16x16x32_bf16(pf1[s], vf1, acc[s][dn], 0, 0, 0);
      }
    }
    cur ^= 1;
  }

  // lsum reductions: lane partial covers key subset for q=lr of each set.
  // Ls rows are wave-private; same-value multi-write across g is benign.
#pragma unroll
  for (int s = 0; s < 4; ++s) {
    float l = (ls0[s][0] + ls0[s][1]) + (ls1[s][0] + ls1[s][1]);
    l += __shfl_xor(l, 16, 64);
    l += __shfl_xor(l, 32, 64);
    Ls[wave * 64 + s * 16 + lr] = l;
  }
  __syncthreads();

  const int bb = bh >> 4, hh = bh & 15;
#pragma unroll
  for (int s = 0; s < 4; ++s) {
#pragma unroll
    for (int r = 0; r < 4; ++r) {
      const int qq = g * 4 + r;
      const float inv = 1.f / fmaxf(Ls[wave * 64 + s * 16 + qq], 1e-30f);
      const int ti = q0 + wave * 64 + s * 16 + qq;
      u16* dst = AO + (((size_t)bb * TSEQ + ti) * NH + hh) * DH + lr;
#pragma unroll
      for (int dn = 0; dn < 4; ++dn)
        dst[dn * 16] = f2bf(acc[s][dn][r] * inv);
    }
  }
}

// ---------------------------------------------------------------------------
// Kernel 3: output projection  out = AO @ Wo^T + bo  (BK=64 two-buffer).
// ---------------------------------------------------------------------------
__global__ __launch_bounds__(256) void out_gemm(
    const int* __restrict__ flag_p,
    const u16* __restrict__ A, const u16* __restrict__ W,
    const void* __restrict__ bias_raw, void* __restrict__ outp)
{
  __shared__ __align__(16) u16 As[2 * 128 * 32];
  __shared__ __align__(16) u16 Bs[2 * 128 * 32];
  const int flag = *flag_p;
  const int t = threadIdx.x;
  const int m0 = blockIdx.x * 128;
  const int n0 = blockIdx.y * 128;
  const int wave = t >> 6, lane = t & 63;
  const int wm = (wave >> 1) * 64, wn = (wave & 1) * 64;
  const int lr = lane & 15, kg = (lane >> 4) * 8;

  const int srow0 = t >> 2, skc = (t & 3) * 8;
  const int srow1 = srow0 + 64;
  const u16* a0 = A + (size_t)(m0 + srow0) * D_MODEL + skc;
  const u16* a1 = A + (size_t)(m0 + srow1) * D_MODEL + skc;
  const u16* b0 = W + (size_t)(n0 + srow0) * D_MODEL + skc;
  const u16* b1 = W + (size_t)(n0 + srow1) * D_MODEL + skc;

  f32x4 acc[4][4] = {};

  for (int kt = 0; kt < D_MODEL / 64; ++kt) {
    gl_lds16(a0,      &As[t * 8]);
    gl_lds16(a1,      &As[(t + 256) * 8]);
    gl_lds16(a0 + 32, &As[4096 + t * 8]);
    gl_lds16(a1 + 32, &As[4096 + (t + 256) * 8]);
    gl_lds16(b0,      &Bs[t * 8]);
    gl_lds16(b1,      &Bs[(t + 256) * 8]);
    gl_lds16(b0 + 32, &Bs[4096 + t * 8]);
    gl_lds16(b1 + 32, &Bs[4096 + (t + 256) * 8]);
    a0 += 64; a1 += 64; b0 += 64; b1 += 64;
    __syncthreads();
#pragma unroll
    for (int h = 0; h < 2; ++h) {
      bf16x8 af[4], bfr[4];
#pragma unroll
      for (int i = 0; i < 4; ++i)
        af[i] = *(const bf16x8*)&As[h * 4096 + (wm + i * 16 + lr) * 32 + kg];
#pragma unroll
      for (int j = 0; j < 4; ++j)
        bfr[j] = *(const bf16x8*)&Bs[h * 4096 + (wn + j * 16 + lr) * 32 + kg];
#pragma unroll
      for (int i = 0; i < 4; ++i)
#pragma unroll
        for (int j = 0; j < 4; ++j)
          acc[i][j] = __builtin_amdgcn_mfma_f32_16x16x32_bf16(af[i], bfr[j], acc[i][j], 0, 0, 0);
    }
    __syncthreads();
  }

#pragma unroll
  for (int j = 0; j < 4; ++j) {
    const int colg = n0 + wn + j * 16 + lr;
    const float bv = flag ? bf2f(((const u16*)bias_raw)[colg])
                          : ((const float*)bias_raw)[colg];
#pragma unroll
    for (int i = 0; i < 4; ++i) {
      const int rowg = m0 + wm + i * 16 + ((lane >> 4) << 2);
      if (flag) {
        u16* dst = (u16*)outp + (size_t)rowg * D_MODEL + colg;
#pragma unroll
        for (int r = 0; r < 4; ++r)
          dst[(size_t)r * D_MODEL] = f2bf(acc[i][j][r] + bv);
      } else {
        float* dst = (float*)outp + (size_t)rowg * D_MODEL + colg;
#pragma unroll
        for (int r = 0; r < 4; ++r)
          dst[(size_t)r * D_MODEL] = acc[i][j][r] + bv;
      }
    }
  }
}

extern "C" void kernel_launch(void* const* d_in, const int* in_sizes, int n_in,
                              void* d_out, int out_size, void* d_ws, size_t ws_size,
                              hipStream_t stream) {
  const void* x  = d_in[0];
  const void* wq = d_in[1];
  const void* wk = d_in[2];
  const void* wv = d_in[3];
  const void* wo = d_in[4];
  const void* bo = d_in[5];
  u16* dout = (u16*)d_out;

  // ws: [flag 16B][Wq][Wk][Wv][Wo bf16, 2MiB ea][K][VT][AO 16MiB ea]
  int* flag = (int*)d_ws;
  u16* wqb = (u16*)d_ws + 8;
  u16* wkb = wqb + WSZ;
  u16* wvb = wkb + WSZ;
  u16* wob = wvb + WSZ;
  u16* kk  = wob + WSZ;
  u16* vt  = kk + NQ;
  u16* ao  = vt + NQ;

  detect_dtype<<<1, 256, 0, stream>>>((const u32*)wq, flag);

  dim3 gc(NQ / (256 * 8), 5);
  convert_inputs<<<gc, dim3(256), 0, stream>>>(
      x, wq, wk, wv, wo, dout, wqb, wkb, wvb, wob, flag);

  dim3 g1(MTOT / 128, D_MODEL / 128, 3);
  qkv_gemm<<<g1, dim3(256), 0, stream>>>(
      flag, (const u16*)x, dout, wqb, wkb, wvb, kk, vt);

  dim3 g2(BATCH * NH, TSEQ / 256, 1);
  flash_attn<<<g2, dim3(256), 0, stream>>>(flag, dout, kk, vt, ao);

  dim3 g3(MTOT / 128, D_MODEL / 128, 1);
  out_gemm<<<g3, dim3(256), 0, stream>>>(flag, ao, wob, bo, d_out);
}

// Round 5
// 287.670 us; speedup vs baseline: 1.1599x; 1.0084x over previous
//
#include <hip/hip_runtime.h>
#include <stdint.h>

#define D_MODEL 1024
#define NH 16
#define DH 64
#define TSEQ 2048
#define BATCH 4
#define MTOT (BATCH*TSEQ)
#define NQ (MTOT*D_MODEL)      // elements in Q/K/VT/AO and in x
#define WSZ (D_MODEL*D_MODEL)  // elements in each weight matrix
// SCALE * log2(e), pre-folded into Q at the qkv epilogue
#define QSCALE 0.18033688f

typedef __attribute__((ext_vector_type(8))) short bf16x8;
typedef __attribute__((ext_vector_type(8))) unsigned short u16x8;
typedef __attribute__((ext_vector_type(4))) float f32x4;
typedef __attribute__((ext_vector_type(2))) float f32x2;
typedef unsigned short u16;
typedef unsigned int u32;

__device__ __forceinline__ void gl_lds16(const void* g, void* l) {
  __builtin_amdgcn_global_load_lds(
      (__attribute__((address_space(1))) void*)g,
      (__attribute__((address_space(3))) void*)l, 16, 0, 0);
}
__device__ __forceinline__ u16 f2bf(float f) {
  u32 u = __builtin_bit_cast(u32, f);
  u = u + 0x7fffu + ((u >> 16) & 1u);
  return (u16)(u >> 16);
}
__device__ __forceinline__ float bf2f(u16 b) {
  u32 u = ((u32)b) << 16;
  return __builtin_bit_cast(float, u);
}

// ---------------------------------------------------------------------------
// Fused raw exp2 + bf16 pack, hazards controlled IN-ASM (round-4 verified:
// 131.8 -> 96.9 us, absmax unchanged). Round-2 lesson: TRANS results consumed
// by a SEPARATE inline-asm within the hazard window give wrong numerics; one
// asm block with 4 back-to-back exps + s_nop 1 before the packs is safe.
// ---------------------------------------------------------------------------
__device__ __forceinline__ void exp2pk4(const f32x4 s, float& e0, float& e1,
                                        float& e2, float& e3, u32& pk01,
                                        u32& pk23) {
  asm("v_exp_f32 %0, %6\n\t"
      "v_exp_f32 %1, %7\n\t"
      "v_exp_f32 %2, %8\n\t"
      "v_exp_f32 %3, %9\n\t"
      "s_nop 1\n\t"
      "v_cvt_pk_bf16_f32 %4, %0, %1\n\t"
      "v_cvt_pk_bf16_f32 %5, %2, %3"
      : "=&v"(e0), "=&v"(e1), "=&v"(e2), "=&v"(e3), "=&v"(pk01), "=&v"(pk23)
      : "v"(s[0]), "v"(s[1]), "v"(s[2]), "v"(s[3]));
}

// ---------------------------------------------------------------------------
// Kernel 0: input dtype detection (1 = bf16, 0 = fp32).
// ---------------------------------------------------------------------------
__global__ __launch_bounds__(256) void detect_dtype(
    const u32* __restrict__ wq_raw, int* __restrict__ flag)
{
  __shared__ int cnt;
  if (threadIdx.x == 0) cnt = 0;
  __syncthreads();
  int c = 0;
  for (int i = threadIdx.x; i < 2048; i += 256) {
    const u32 e = (wq_raw[i] >> 7) & 0xFFu;
    if (e >= 90u && e <= 126u) ++c;
  }
  atomicAdd(&cnt, c);
  __syncthreads();
  if (threadIdx.x == 0) *flag = (cnt > 1024) ? 1 : 0;
}

// ---------------------------------------------------------------------------
// Kernel 0b: convert inputs to bf16 — fp32 path ONLY. ROUND-5: when flag=1
// (bf16 inputs) the GEMMs read the raw weight pointers directly, so this
// kernel early-exits entirely (was copying 8 MB of weights for nothing).
// seg 0 = x -> d_out low half, 1..4 = Wq,Wk,Wv,Wo -> d_ws.
// ---------------------------------------------------------------------------
__global__ __launch_bounds__(256) void convert_inputs(
    const void* __restrict__ x, const void* __restrict__ wq,
    const void* __restrict__ wk, const void* __restrict__ wv,
    const void* __restrict__ wo,
    u16* __restrict__ xb, u16* __restrict__ wqb, u16* __restrict__ wkb,
    u16* __restrict__ wvb, u16* __restrict__ wob,
    const int* __restrict__ flag_p)
{
  if (*flag_p) return;  // bf16 inputs: consumers read raw pointers directly
  const int seg = blockIdx.y;
  const void* src; u16* dst; int n;
  switch (seg) {
    case 0:  src = x;  dst = xb;  n = NQ;  break;
    case 1:  src = wq; dst = wqb; n = WSZ; break;
    case 2:  src = wk; dst = wkb; n = WSZ; break;
    case 3:  src = wv; dst = wvb; n = WSZ; break;
    default: src = wo; dst = wob; n = WSZ; break;
  }
  const int idx = (blockIdx.x * 256 + threadIdx.x) * 8;
  if (idx >= n) return;
  const float4 f0 = *(const float4*)((const float*)src + idx);
  const float4 f1 = *(const float4*)((const float*)src + idx + 4);
  union { u16 s[8]; u16x8 v; } u;
  u.s[0] = f2bf(f0.x); u.s[1] = f2bf(f0.y); u.s[2] = f2bf(f0.z); u.s[3] = f2bf(f0.w);
  u.s[4] = f2bf(f1.x); u.s[5] = f2bf(f1.y); u.s[6] = f2bf(f1.z); u.s[7] = f2bf(f1.w);
  *(u16x8*)(dst + idx) = u.v;
}

// ---------------------------------------------------------------------------
// Kernel 1: QKV projection. BK=64 via TWO BK=32 buffers per barrier-pair.
// z=0 -> Q^T [B,H,64,T] (pre-scaled); z=1 -> K [B,H,T,64]; z=2 -> V^T.
// ROUND-5: (a) raw-weight read when flag=1; (b) XCD-contiguous m-block
// swizzle: XCD j (= blockIdx.x % 8) owns m-blocks 8j..8j+7 for every (y,z),
// keeping its 2 MB A-slice L2-resident.
// ---------------------------------------------------------------------------
__global__ __launch_bounds__(256) void qkv_gemm(
    const int* __restrict__ flag_p, const u16* __restrict__ x_raw,
    u16* __restrict__ dout,
    const u16* __restrict__ Wq, const u16* __restrict__ Wk,
    const u16* __restrict__ Wv,
    const void* __restrict__ wq_r, const void* __restrict__ wk_r,
    const void* __restrict__ wv_r,
    u16* __restrict__ Ko, u16* __restrict__ VTo)
{
  __shared__ __align__(16) u16 As[2 * 128 * 32];
  __shared__ __align__(16) u16 Bs[2 * 128 * 32];
  const int flag = *flag_p;
  const u16* __restrict__ X = flag ? x_raw : dout;  // converted x in dout low
  u16* __restrict__ QTo = flag ? dout : dout + NQ;
  const int t = threadIdx.x;
  const int z = blockIdx.z;
  const u16* __restrict__ Wc = (z == 0) ? Wq : (z == 1) ? Wk : Wv;
  const u16* __restrict__ Wr = (const u16*)((z == 0) ? wq_r : (z == 1) ? wk_r : wv_r);
  const u16* __restrict__ W = flag ? Wr : Wc;
  const int bx = blockIdx.x;
  const int mb = ((bx & 7) << 3) | (bx >> 3);  // bijective on 64, XCD-chunked
  const int m0 = mb * 128;
  const int n0 = blockIdx.y * 128;
  const int wave = t >> 6, lane = t & 63;
  const int wm = (wave >> 1) * 64, wn = (wave & 1) * 64;
  const int lr = lane & 15, kg = (lane >> 4) * 8;

  const int srow0 = t >> 2, skc = (t & 3) * 8;
  const int srow1 = srow0 + 64;
  const u16* a0 = X + (size_t)(m0 + srow0) * D_MODEL + skc;
  const u16* a1 = X + (size_t)(m0 + srow1) * D_MODEL + skc;
  const u16* b0 = W + (size_t)(n0 + srow0) * D_MODEL + skc;
  const u16* b1 = W + (size_t)(n0 + srow1) * D_MODEL + skc;

  f32x4 acc[4][4] = {};

  for (int kt = 0; kt < D_MODEL / 64; ++kt) {
    gl_lds16(a0,      &As[t * 8]);
    gl_lds16(a1,      &As[(t + 256) * 8]);
    gl_lds16(a0 + 32, &As[4096 + t * 8]);
    gl_lds16(a1 + 32, &As[4096 + (t + 256) * 8]);
    gl_lds16(b0,      &Bs[t * 8]);
    gl_lds16(b1,      &Bs[(t + 256) * 8]);
    gl_lds16(b0 + 32, &Bs[4096 + t * 8]);
    gl_lds16(b1 + 32, &Bs[4096 + (t + 256) * 8]);
    a0 += 64; a1 += 64; b0 += 64; b1 += 64;
    __syncthreads();
#pragma unroll
    for (int h = 0; h < 2; ++h) {
      bf16x8 af[4], bfr[4];
#pragma unroll
      for (int i = 0; i < 4; ++i)
        af[i] = *(const bf16x8*)&As[h * 4096 + (wm + i * 16 + lr) * 32 + kg];
#pragma unroll
      for (int j = 0; j < 4; ++j)
        bfr[j] = *(const bf16x8*)&Bs[h * 4096 + (wn + j * 16 + lr) * 32 + kg];
#pragma unroll
      for (int i = 0; i < 4; ++i)
#pragma unroll
        for (int j = 0; j < 4; ++j)
          acc[i][j] = __builtin_amdgcn_mfma_f32_16x16x32_bf16(af[i], bfr[j], acc[i][j], 0, 0, 0);
    }
    __syncthreads();
  }

  // C/D layout: col = lane&15, row = (lane>>4)*4 + reg
  const int bidx = m0 >> 11;
  if (z == 1) {
    // K: [B,H,T,64], scalar stores (d-contiguous rows for flash staging)
#pragma unroll
    for (int i = 0; i < 4; ++i) {
      const int rowg = m0 + wm + i * 16 + ((lane >> 4) << 2);
      const int tq = rowg & (TSEQ - 1);
#pragma unroll
      for (int j = 0; j < 4; ++j) {
        const int colg = n0 + wn + j * 16 + lr;
        const int h = colg >> 6, d = colg & 63;
        u16* dst = Ko + ((size_t)(bidx * NH + h) * TSEQ + tq) * DH + d;
#pragma unroll
        for (int r = 0; r < 4; ++r)
          dst[(size_t)r * DH] = f2bf(acc[i][j][r]);
      }
    }
  } else {
    // Q^T (scaled) and V^T: [B,H,64,T], vectorized 8B stores along t
    u16* O = (z == 0) ? QTo : VTo;
    const float sc = (z == 0) ? QSCALE : 1.0f;
#pragma unroll
    for (int i = 0; i < 4; ++i) {
      const int rowg = m0 + wm + i * 16 + ((lane >> 4) << 2);
      const int tq = rowg & (TSEQ - 1);  // multiple of 4 -> 8B aligned
#pragma unroll
      for (int j = 0; j < 4; ++j) {
        const int colg = n0 + wn + j * 16 + lr;
        const int h = colg >> 6, d = colg & 63;
        union { u16 s[4]; uint2 v; } u;
#pragma unroll
        for (int r = 0; r < 4; ++r) u.s[r] = f2bf(acc[i][j][r] * sc);
        *(uint2*)&O[((size_t)(bidx * NH + h) * DH + d) * TSEQ + tq] = u.v;
      }
    }
  }
}

// ---------------------------------------------------------------------------
// Kernel 2: flash attention. 64 q-rows per wave (4 q-sets), 256 q per block;
// each K/V LDS fragment feeds 4 MFMA. Double-buffered K/V staging, 1 barrier
// per tile. Softmax exp via fused in-asm exp2pk4 (round-4).
// ROUND-5: jn-split PV overlap — QK key-rows 0..31 (jn 0,1) -> issue pf0
// reads (in-order DS pipe: they complete without waiting on later writes;
// disjoint regions) -> QK jn 2,3 (its exp/pack VALU covers pf0's DS latency)
// -> PV key-half 0 -> pf1 reads -> PV key-half 1. Halves the exposed
// P-write->read wait that gated the first PV MFMA.
// Grid = (64 bh, 8 qblk) = 512 blocks = 2 blocks/CU; XCD: bh % 8.
// ---------------------------------------------------------------------------
__global__ __launch_bounds__(256) void flash_attn(
    const int* __restrict__ flag_p, const u16* __restrict__ dout,
    const u16* __restrict__ K, const u16* __restrict__ VT,
    u16* __restrict__ AO)
{
  __shared__ __align__(16) u16 Ks[2][2 * 64 * 32];  // [buf][half][64 keys][32 d]
  __shared__ __align__(16) u16 Vs[2][2 * 64 * 32];  // [buf][half][64 d][32 keys]
  __shared__ __align__(16) u16 Ps[4 * 64 * 72];     // per-wave [64 q][64+8 keys]
  __shared__ float Ls[4 * 64];
  const int flag = *flag_p;
  const u16* __restrict__ QT = flag ? dout : dout + NQ;
  const int t = threadIdx.x;
  const int wave = t >> 6, lane = t & 63;
  const int lr = lane & 15, g = lane >> 4, kg = g * 8;
  const int bh = blockIdx.x;          // fastest grid dim -> XCD = bh % 8
  const int q0 = blockIdx.y * 256;
  const u16* __restrict__ QTh = QT + (size_t)bh * DH * TSEQ;  // [64 d][T]
  const u16* __restrict__ Kh = K + (size_t)bh * TSEQ * DH;
  const u16* __restrict__ Vh = VT + (size_t)bh * DH * TSEQ;

  // 8 Q B-fragments per wave: q-sets s=0..3 (16 q each), d-halves 0/1.
  const int qi = q0 + wave * 64 + lr;
  bf16x8 qf[8];
#pragma unroll
  for (int s = 0; s < 4; ++s) {
    union { u16 v[8]; bf16x8 b; } u0, u1;
#pragma unroll
    for (int j = 0; j < 8; ++j) {
      u0.v[j] = QTh[(size_t)(kg + j) * TSEQ + qi + s * 16];
      u1.v[j] = QTh[(size_t)(32 + kg + j) * TSEQ + qi + s * 16];
    }
    qf[s * 2] = u0.b; qf[s * 2 + 1] = u1.b;
  }

  f32x4 acc[4][4] = {};                 // [set][dn]
  f32x2 ls0[4] = {}, ls1[4] = {};

  const int srow = t >> 2, skc = (t & 3) * 8;
  const u16* kb = Kh + (size_t)srow * DH + skc;
  const u16* vb = Vh + (size_t)srow * TSEQ + skc;
  u16* const pw = &Ps[wave * 64 * 72];  // q-set s at rows s*16..s*16+15

  // prologue: prefetch tile 0 into buffer 0
  gl_lds16(kb,      &Ks[0][t * 8]);          // keys, d 0..31
  gl_lds16(kb + 32, &Ks[0][(t + 256) * 8]);  // keys, d 32..63
  gl_lds16(vb,      &Vs[0][t * 8]);          // [d][keys 0..31]
  gl_lds16(vb + 32, &Vs[0][(t + 256) * 8]);  // [d][keys 32..63]
  kb += 64 * DH; vb += 64;

  int cur = 0;
  for (int j0 = 0; j0 < TSEQ; j0 += 64) {
    // single barrier per tile: drains cur-buf loads (issued a full tile ago)
    // and guarantees everyone is done reading buf^1 before we overwrite it.
    __syncthreads();
    if (j0 + 64 < TSEQ) {
      gl_lds16(kb,      &Ks[cur ^ 1][t * 8]);
      gl_lds16(kb + 32, &Ks[cur ^ 1][(t + 256) * 8]);
      gl_lds16(vb,      &Vs[cur ^ 1][t * 8]);
      gl_lds16(vb + 32, &Vs[cur ^ 1][(t + 256) * 8]);
      kb += 64 * DH; vb += 64;
    }
    const u16* __restrict__ Kc = Ks[cur];
    const u16* __restrict__ Vc = Vs[cur];

    // --- QK key-rows 0..31 (jn = 0,1) ---
#pragma unroll
    for (int jn = 0; jn < 2; ++jn) {
      const bf16x8 kf0 = *(const bf16x8*)&Kc[(jn * 16 + lr) * 32 + kg];
      const bf16x8 kf1 = *(const bf16x8*)&Kc[2048 + (jn * 16 + lr) * 32 + kg];
#pragma unroll
      for (int s = 0; s < 4; ++s) {
        f32x4 sS = {};
        sS = __builtin_amdgcn_mfma_f32_16x16x32_bf16(kf0, qf[s * 2],     sS, 0, 0, 0);
        sS = __builtin_amdgcn_mfma_f32_16x16x32_bf16(kf1, qf[s * 2 + 1], sS, 0, 0, 0);
        float e0, e1, e2, e3;
        uint2 w;
        exp2pk4(sS, e0, e1, e2, e3, w.x, w.y);
        ls0[s] += (f32x2){e0, e1};
        ls1[s] += (f32x2){e2, e3};
        *(uint2*)&pw[s * 16 * 72 + lr * 72 + jn * 16 + g * 4] = w;
      }
    }

    // pf0 (keys 0..31) issued now: in-order DS -> completes after the jn0/1
    // writes (same region) but does NOT wait on the jn2/3 writes below.
    bf16x8 pf0[4];
#pragma unroll
    for (int s = 0; s < 4; ++s)
      pf0[s] = *(const bf16x8*)&pw[s * 16 * 72 + lr * 72 + kg];

    // --- QK key-rows 32..63 (jn = 2,3): VALU here covers pf0 DS latency ---
#pragma unroll
    for (int jn = 2; jn < 4; ++jn) {
      const bf16x8 kf0 = *(const bf16x8*)&Kc[(jn * 16 + lr) * 32 + kg];
      const bf16x8 kf1 = *(const bf16x8*)&Kc[2048 + (jn * 16 + lr) * 32 + kg];
#pragma unroll
      for (int s = 0; s < 4; ++s) {
        f32x4 sS = {};
        sS = __builtin_amdgcn_mfma_f32_16x16x32_bf16(kf0, qf[s * 2],     sS, 0, 0, 0);
        sS = __builtin_amdgcn_mfma_f32_16x16x32_bf16(kf1, qf[s * 2 + 1], sS, 0, 0, 0);
        float e0, e1, e2, e3;
        uint2 w;
        exp2pk4(sS, e0, e1, e2, e3, w.x, w.y);
        ls0[s] += (f32x2){e0, e1};
        ls1[s] += (f32x2){e2, e3};
        *(uint2*)&pw[s * 16 * 72 + lr * 72 + jn * 16 + g * 4] = w;
      }
    }

    // --- PV key-half 0 ---
#pragma unroll
    for (int dn = 0; dn < 4; ++dn) {
      const bf16x8 vf0 = *(const bf16x8*)&Vc[(dn * 16 + lr) * 32 + kg];
#pragma unroll
      for (int s = 0; s < 4; ++s)
        acc[s][dn] = __builtin_amdgcn_mfma_f32_16x16x32_bf16(pf0[s], vf0, acc[s][dn], 0, 0, 0);
    }

    // pf1 (keys 32..63), then PV key-half 1
    bf16x8 pf1[4];
#pragma unroll
    for (int s = 0; s < 4; ++s)
      pf1[s] = *(const bf16x8*)&pw[s * 16 * 72 + lr * 72 + 32 + kg];
#pragma unroll
    for (int dn = 0; dn < 4; ++dn) {
      const bf16x8 vf1 = *(const bf16x8*)&Vc[2048 + (dn * 16 + lr) * 32 + kg];
#pragma unroll
      for (int s = 0; s < 4; ++s)
        acc[s][dn] = __builtin_amdgcn_mfma_f32_16x16x32_bf16(pf1[s], vf1, acc[s][dn], 0, 0, 0);
    }
    cur ^= 1;
  }

  // lsum reductions: lane partial covers key subset for q=lr of each set.
#pragma unroll
  for (int s = 0; s < 4; ++s) {
    float l = (ls0[s][0] + ls0[s][1]) + (ls1[s][0] + ls1[s][1]);
    l += __shfl_xor(l, 16, 64);
    l += __shfl_xor(l, 32, 64);
    Ls[wave * 64 + s * 16 + lr] = l;
  }
  __syncthreads();

  const int bb = bh >> 4, hh = bh & 15;
#pragma unroll
  for (int s = 0; s < 4; ++s) {
#pragma unroll
    for (int r = 0; r < 4; ++r) {
      const int qq = g * 4 + r;
      const float inv = 1.f / fmaxf(Ls[wave * 64 + s * 16 + qq], 1e-30f);
      const int ti = q0 + wave * 64 + s * 16 + qq;
      u16* dst = AO + (((size_t)bb * TSEQ + ti) * NH + hh) * DH + lr;
#pragma unroll
      for (int dn = 0; dn < 4; ++dn)
        dst[dn * 16] = f2bf(acc[s][dn][r] * inv);
    }
  }
}

// ---------------------------------------------------------------------------
// Kernel 3: output projection  out = AO @ Wo^T + bo  (BK=64 two-buffer).
// ROUND-5: raw-Wo read when flag=1 + XCD-contiguous m-block swizzle.
// ---------------------------------------------------------------------------
__global__ __launch_bounds__(256) void out_gemm(
    const int* __restrict__ flag_p,
    const u16* __restrict__ A, const u16* __restrict__ W,
    const void* __restrict__ wo_r,
    const void* __restrict__ bias_raw, void* __restrict__ outp)
{
  __shared__ __align__(16) u16 As[2 * 128 * 32];
  __shared__ __align__(16) u16 Bs[2 * 128 * 32];
  const int flag = *flag_p;
  const u16* __restrict__ Wm = flag ? (const u16*)wo_r : W;
  const int t = threadIdx.x;
  const int bx = blockIdx.x;
  const int mb = ((bx & 7) << 3) | (bx >> 3);  // bijective on 64, XCD-chunked
  const int m0 = mb * 128;
  const int n0 = blockIdx.y * 128;
  const int wave = t >> 6, lane = t & 63;
  const int wm = (wave >> 1) * 64, wn = (wave & 1) * 64;
  const int lr = lane & 15, kg = (lane >> 4) * 8;

  const int srow0 = t >> 2, skc = (t & 3) * 8;
  const int srow1 = srow0 + 64;
  const u16* a0 = A + (size_t)(m0 + srow0) * D_MODEL + skc;
  const u16* a1 = A + (size_t)(m0 + srow1) * D_MODEL + skc;
  const u16* b0 = Wm + (size_t)(n0 + srow0) * D_MODEL + skc;
  const u16* b1 = Wm + (size_t)(n0 + srow1) * D_MODEL + skc;

  f32x4 acc[4][4] = {};

  for (int kt = 0; kt < D_MODEL / 64; ++kt) {
    gl_lds16(a0,      &As[t * 8]);
    gl_lds16(a1,      &As[(t + 256) * 8]);
    gl_lds16(a0 + 32, &As[4096 + t * 8]);
    gl_lds16(a1 + 32, &As[4096 + (t + 256) * 8]);
    gl_lds16(b0,      &Bs[t * 8]);
    gl_lds16(b1,      &Bs[(t + 256) * 8]);
    gl_lds16(b0 + 32, &Bs[4096 + t * 8]);
    gl_lds16(b1 + 32, &Bs[4096 + (t + 256) * 8]);
    a0 += 64; a1 += 64; b0 += 64; b1 += 64;
    __syncthreads();
#pragma unroll
    for (int h = 0; h < 2; ++h) {
      bf16x8 af[4], bfr[4];
#pragma unroll
      for (int i = 0; i < 4; ++i)
        af[i] = *(const bf16x8*)&As[h * 4096 + (wm + i * 16 + lr) * 32 + kg];
#pragma unroll
      for (int j = 0; j < 4; ++j)
        bfr[j] = *(const bf16x8*)&Bs[h * 4096 + (wn + j * 16 + lr) * 32 + kg];
#pragma unroll
      for (int i = 0; i < 4; ++i)
#pragma unroll
        for (int j = 0; j < 4; ++j)
          acc[i][j] = __builtin_amdgcn_mfma_f32_16x16x32_bf16(af[i], bfr[j], acc[i][j], 0, 0, 0);
    }
    __syncthreads();
  }

#pragma unroll
  for (int j = 0; j < 4; ++j) {
    const int colg = n0 + wn + j * 16 + lr;
    const float bv = flag ? bf2f(((const u16*)bias_raw)[colg])
                          : ((const float*)bias_raw)[colg];
#pragma unroll
    for (int i = 0; i < 4; ++i) {
      const int rowg = m0 + wm + i * 16 + ((lane >> 4) << 2);
      if (flag) {
        u16* dst = (u16*)outp + (size_t)rowg * D_MODEL + colg;
#pragma unroll
        for (int r = 0; r < 4; ++r)
          dst[(size_t)r * D_MODEL] = f2bf(acc[i][j][r] + bv);
      } else {
        float* dst = (float*)outp + (size_t)rowg * D_MODEL + colg;
#pragma unroll
        for (int r = 0; r < 4; ++r)
          dst[(size_t)r * D_MODEL] = acc[i][j][r] + bv;
      }
    }
  }
}

extern "C" void kernel_launch(void* const* d_in, const int* in_sizes, int n_in,
                              void* d_out, int out_size, void* d_ws, size_t ws_size,
                              hipStream_t stream) {
  const void* x  = d_in[0];
  const void* wq = d_in[1];
  const void* wk = d_in[2];
  const void* wv = d_in[3];
  const void* wo = d_in[4];
  const void* bo = d_in[5];
  u16* dout = (u16*)d_out;

  // ws: [flag 16B][Wq][Wk][Wv][Wo bf16, 2MiB ea][K][VT][AO 16MiB ea]
  int* flag = (int*)d_ws;
  u16* wqb = (u16*)d_ws + 8;
  u16* wkb = wqb + WSZ;
  u16* wvb = wkb + WSZ;
  u16* wob = wvb + WSZ;
  u16* kk  = wob + WSZ;
  u16* vt  = kk + NQ;
  u16* ao  = vt + NQ;

  detect_dtype<<<1, 256, 0, stream>>>((const u32*)wq, flag);

  dim3 gc(NQ / (256 * 8), 5);
  convert_inputs<<<gc, dim3(256), 0, stream>>>(
      x, wq, wk, wv, wo, dout, wqb, wkb, wvb, wob, flag);

  dim3 g1(MTOT / 128, D_MODEL / 128, 3);
  qkv_gemm<<<g1, dim3(256), 0, stream>>>(
      flag, (const u16*)x, dout, wqb, wkb, wvb, wq, wk, wv, kk, vt);

  dim3 g2(BATCH * NH, TSEQ / 256, 1);
  flash_attn<<<g2, dim3(256), 0, stream>>>(flag, dout, kk, vt, ao);

  dim3 g3(MTOT / 128, D_MODEL / 128, 1);
  out_gemm<<<g3, dim3(256), 0, stream>>>(flag, ao, wob, wo, bo, d_out);
}

// Round 6
// 268.283 us; speedup vs baseline: 1.2437x; 1.0723x over previous
//
#include <hip/hip_runtime.h>
#include <stdint.h>

#define D_MODEL 1024
#define NH 16
#define DH 64
#define TSEQ 2048
#define BATCH 4
#define MTOT (BATCH*TSEQ)
#define NQ (MTOT*D_MODEL)      // elements in Q/K/VT/AO and in x
#define WSZ (D_MODEL*D_MODEL)  // elements in each weight matrix
// SCALE * log2(e), pre-folded into Q at the qkv epilogue
#define QSCALE 0.18033688f

typedef __attribute__((ext_vector_type(8))) short bf16x8;
typedef __attribute__((ext_vector_type(8))) unsigned short u16x8;
typedef __attribute__((ext_vector_type(4))) float f32x4;
typedef __attribute__((ext_vector_type(2))) float f32x2;
typedef unsigned short u16;
typedef unsigned int u32;

__device__ __forceinline__ void gl_lds16(const void* g, void* l) {
  __builtin_amdgcn_global_load_lds(
      (__attribute__((address_space(1))) void*)g,
      (__attribute__((address_space(3))) void*)l, 16, 0, 0);
}
__device__ __forceinline__ u16 f2bf(float f) {
  u32 u = __builtin_bit_cast(u32, f);
  u = u + 0x7fffu + ((u >> 16) & 1u);
  return (u16)(u >> 16);
}
__device__ __forceinline__ float bf2f(u16 b) {
  u32 u = ((u32)b) << 16;
  return __builtin_bit_cast(float, u);
}

// ---------------------------------------------------------------------------
// Fused raw exp2 + bf16 pack, hazards controlled IN-ASM (round-4 verified:
// 131.8 -> 96.9 us, absmax unchanged). Round-2 lesson: TRANS results consumed
// by a SEPARATE inline-asm within the hazard window gave wrong numerics; one
// asm block with 4 back-to-back exps + s_nop 1 before the packs is safe.
// ---------------------------------------------------------------------------
__device__ __forceinline__ void exp2pk4(const f32x4 s, float& e0, float& e1,
                                        float& e2, float& e3, u32& pk01,
                                        u32& pk23) {
  asm("v_exp_f32 %0, %6\n\t"
      "v_exp_f32 %1, %7\n\t"
      "v_exp_f32 %2, %8\n\t"
      "v_exp_f32 %3, %9\n\t"
      "s_nop 1\n\t"
      "v_cvt_pk_bf16_f32 %4, %0, %1\n\t"
      "v_cvt_pk_bf16_f32 %5, %2, %3"
      : "=&v"(e0), "=&v"(e1), "=&v"(e2), "=&v"(e3), "=&v"(pk01), "=&v"(pk23)
      : "v"(s[0]), "v"(s[1]), "v"(s[2]), "v"(s[3]));
}

// ---------------------------------------------------------------------------
// Kernel 0: input dtype detection (1 = bf16, 0 = fp32).
// ---------------------------------------------------------------------------
__global__ __launch_bounds__(256) void detect_dtype(
    const u32* __restrict__ wq_raw, int* __restrict__ flag)
{
  __shared__ int cnt;
  if (threadIdx.x == 0) cnt = 0;
  __syncthreads();
  int c = 0;
  for (int i = threadIdx.x; i < 2048; i += 256) {
    const u32 e = (wq_raw[i] >> 7) & 0xFFu;
    if (e >= 90u && e <= 126u) ++c;
  }
  atomicAdd(&cnt, c);
  __syncthreads();
  if (threadIdx.x == 0) *flag = (cnt > 1024) ? 1 : 0;
}

// ---------------------------------------------------------------------------
// Kernel 0b: convert inputs to bf16 — fp32 path ONLY (flag=1 early-exits;
// consumers read raw pointers directly).
// ---------------------------------------------------------------------------
__global__ __launch_bounds__(256) void convert_inputs(
    const void* __restrict__ x, const void* __restrict__ wq,
    const void* __restrict__ wk, const void* __restrict__ wv,
    const void* __restrict__ wo,
    u16* __restrict__ xb, u16* __restrict__ wqb, u16* __restrict__ wkb,
    u16* __restrict__ wvb, u16* __restrict__ wob,
    const int* __restrict__ flag_p)
{
  if (*flag_p) return;  // bf16 inputs: consumers read raw pointers directly
  const int seg = blockIdx.y;
  const void* src; u16* dst; int n;
  switch (seg) {
    case 0:  src = x;  dst = xb;  n = NQ;  break;
    case 1:  src = wq; dst = wqb; n = WSZ; break;
    case 2:  src = wk; dst = wkb; n = WSZ; break;
    case 3:  src = wv; dst = wvb; n = WSZ; break;
    default: src = wo; dst = wob; n = WSZ; break;
  }
  const int idx = (blockIdx.x * 256 + threadIdx.x) * 8;
  if (idx >= n) return;
  const float4 f0 = *(const float4*)((const float*)src + idx);
  const float4 f1 = *(const float4*)((const float*)src + idx + 4);
  union { u16 s[8]; u16x8 v; } u;
  u.s[0] = f2bf(f0.x); u.s[1] = f2bf(f0.y); u.s[2] = f2bf(f0.z); u.s[3] = f2bf(f0.w);
  u.s[4] = f2bf(f1.x); u.s[5] = f2bf(f1.y); u.s[6] = f2bf(f1.z); u.s[7] = f2bf(f1.w);
  *(u16x8*)(dst + idx) = u.v;
}

// ---------------------------------------------------------------------------
// Kernel 1: FUSED QKV projection (ROUND-6). One K-loop stages the A-tile (X)
// ONCE plus all three B-tiles (Wq,Wk,Wv), then runs 96 MFMA per barrier-pair
// on 3 accumulator sets with the A-fragments shared. vs the old per-z kernel:
// A-staging traffic /3, ds_read per MFMA /1.5, barrier+vmcnt(0) stall
// amortized 3x (that stall is ~72% of a 2-phase GEMM loop, learn_hip m233).
// LDS 64 KB -> 2 blocks/CU; grid (64,8)=512 = exactly 2/CU, no tail.
// K-output computed with SWAPPED operands mfma(bk, af) -> D[d][t]: reg r
// walks d, so K[t][d0..d0+3] is one 8B store (was 64 scalar u16 stores).
// Outputs: Q^T [B,H,64,T] (pre-scaled), K [B,H,T,64], V^T [B,H,64,T].
// ---------------------------------------------------------------------------
__global__ __launch_bounds__(256, 2) void qkv_gemm(
    const int* __restrict__ flag_p, const u16* __restrict__ x_raw,
    u16* __restrict__ dout,
    const u16* __restrict__ Wq, const u16* __restrict__ Wk,
    const u16* __restrict__ Wv,
    const void* __restrict__ wq_r, const void* __restrict__ wk_r,
    const void* __restrict__ wv_r,
    u16* __restrict__ Ko, u16* __restrict__ VTo)
{
  __shared__ __align__(16) u16 As [2 * 128 * 32];
  __shared__ __align__(16) u16 Bqs[2 * 128 * 32];
  __shared__ __align__(16) u16 Bks[2 * 128 * 32];
  __shared__ __align__(16) u16 Bvs[2 * 128 * 32];
  const int flag = *flag_p;
  const u16* __restrict__ X  = flag ? x_raw : dout;  // converted x in dout low
  u16* __restrict__ QTo = flag ? dout : dout + NQ;
  const u16* __restrict__ WQ = flag ? (const u16*)wq_r : Wq;
  const u16* __restrict__ WK = flag ? (const u16*)wk_r : Wk;
  const u16* __restrict__ WV = flag ? (const u16*)wv_r : Wv;
  const int t = threadIdx.x;
  const int m0 = blockIdx.x * 128;
  const int n0 = blockIdx.y * 128;
  const int wave = t >> 6, lane = t & 63;
  const int wm = (wave >> 1) * 64, wn = (wave & 1) * 64;
  const int lr = lane & 15, g = lane >> 4, kg = g * 8;

  const int srow0 = t >> 2, skc = (t & 3) * 8;
  const int srow1 = srow0 + 64;
  const u16* a0 = X  + (size_t)(m0 + srow0) * D_MODEL + skc;
  const u16* a1 = X  + (size_t)(m0 + srow1) * D_MODEL + skc;
  const u16* q0p = WQ + (size_t)(n0 + srow0) * D_MODEL + skc;
  const u16* q1p = WQ + (size_t)(n0 + srow1) * D_MODEL + skc;
  const u16* k0p = WK + (size_t)(n0 + srow0) * D_MODEL + skc;
  const u16* k1p = WK + (size_t)(n0 + srow1) * D_MODEL + skc;
  const u16* v0p = WV + (size_t)(n0 + srow0) * D_MODEL + skc;
  const u16* v1p = WV + (size_t)(n0 + srow1) * D_MODEL + skc;

  f32x4 accq[4][4] = {};  // [i=m][j=n]
  f32x4 acck[4][4] = {};  // [j=n][i=m]  (swapped-operand output D[d][t])
  f32x4 accv[4][4] = {};  // [i=m][j=n]

  for (int kt = 0; kt < D_MODEL / 64; ++kt) {
    gl_lds16(a0,       &As [t * 8]);
    gl_lds16(a1,       &As [(t + 256) * 8]);
    gl_lds16(a0 + 32,  &As [4096 + t * 8]);
    gl_lds16(a1 + 32,  &As [4096 + (t + 256) * 8]);
    gl_lds16(q0p,      &Bqs[t * 8]);
    gl_lds16(q1p,      &Bqs[(t + 256) * 8]);
    gl_lds16(q0p + 32, &Bqs[4096 + t * 8]);
    gl_lds16(q1p + 32, &Bqs[4096 + (t + 256) * 8]);
    gl_lds16(k0p,      &Bks[t * 8]);
    gl_lds16(k1p,      &Bks[(t + 256) * 8]);
    gl_lds16(k0p + 32, &Bks[4096 + t * 8]);
    gl_lds16(k1p + 32, &Bks[4096 + (t + 256) * 8]);
    gl_lds16(v0p,      &Bvs[t * 8]);
    gl_lds16(v1p,      &Bvs[(t + 256) * 8]);
    gl_lds16(v0p + 32, &Bvs[4096 + t * 8]);
    gl_lds16(v1p + 32, &Bvs[4096 + (t + 256) * 8]);
    a0 += 64; a1 += 64; q0p += 64; q1p += 64;
    k0p += 64; k1p += 64; v0p += 64; v1p += 64;
    __syncthreads();
#pragma unroll
    for (int h = 0; h < 2; ++h) {
      bf16x8 af[4], bfr[4];
#pragma unroll
      for (int i = 0; i < 4; ++i)
        af[i] = *(const bf16x8*)&As[h * 4096 + (wm + i * 16 + lr) * 32 + kg];
      // Q
#pragma unroll
      for (int j = 0; j < 4; ++j)
        bfr[j] = *(const bf16x8*)&Bqs[h * 4096 + (wn + j * 16 + lr) * 32 + kg];
#pragma unroll
      for (int i = 0; i < 4; ++i)
#pragma unroll
        for (int j = 0; j < 4; ++j)
          accq[i][j] = __builtin_amdgcn_mfma_f32_16x16x32_bf16(af[i], bfr[j], accq[i][j], 0, 0, 0);
      // K (swapped: A = W-fragment -> rows = d, cols = t)
#pragma unroll
      for (int j = 0; j < 4; ++j)
        bfr[j] = *(const bf16x8*)&Bks[h * 4096 + (wn + j * 16 + lr) * 32 + kg];
#pragma unroll
      for (int j = 0; j < 4; ++j)
#pragma unroll
        for (int i = 0; i < 4; ++i)
          acck[j][i] = __builtin_amdgcn_mfma_f32_16x16x32_bf16(bfr[j], af[i], acck[j][i], 0, 0, 0);
      // V
#pragma unroll
      for (int j = 0; j < 4; ++j)
        bfr[j] = *(const bf16x8*)&Bvs[h * 4096 + (wn + j * 16 + lr) * 32 + kg];
#pragma unroll
      for (int i = 0; i < 4; ++i)
#pragma unroll
        for (int j = 0; j < 4; ++j)
          accv[i][j] = __builtin_amdgcn_mfma_f32_16x16x32_bf16(af[i], bfr[j], accv[i][j], 0, 0, 0);
    }
    __syncthreads();
  }

  // C/D layout: col = lane&15, row = (lane>>4)*4 + reg
  const int bidx = m0 >> 11;
  // --- Q^T (scaled) and V^T: [B,H,64,T], vectorized 8B stores along t ---
#pragma unroll
  for (int zz = 0; zz < 2; ++zz) {
    u16* O = zz ? VTo : QTo;
    const float sc = zz ? 1.0f : QSCALE;
#pragma unroll
    for (int i = 0; i < 4; ++i) {
      const int rowg = m0 + wm + i * 16 + (g << 2);
      const int tq = rowg & (TSEQ - 1);  // multiple of 4 -> 8B aligned
#pragma unroll
      for (int j = 0; j < 4; ++j) {
        const int colg = n0 + wn + j * 16 + lr;
        const int h = colg >> 6, d = colg & 63;
        const f32x4 a = zz ? accv[i][j] : accq[i][j];
        union { u16 s[4]; uint2 v; } u;
#pragma unroll
        for (int r = 0; r < 4; ++r) u.s[r] = f2bf(a[r] * sc);
        *(uint2*)&O[((size_t)(bidx * NH + h) * DH + d) * TSEQ + tq] = u.v;
      }
    }
  }
  // --- K: [B,H,T,64]. Swapped output D[d][t]: col=lr -> t, row=g*4+r -> d.
  //     reg r walks d => one 8B store per (j,i). ---
#pragma unroll
  for (int j = 0; j < 4; ++j) {
    const int dg = n0 + wn + j * 16 + (g << 2);  // d-global base (r adds 0..3)
    const int hh = dg >> 6, d0 = dg & 63;        // head fixed over r
#pragma unroll
    for (int i = 0; i < 4; ++i) {
      const int tg = m0 + wm + i * 16 + lr;
      const int tq = tg & (TSEQ - 1);
      union { u16 s[4]; uint2 v; } u;
#pragma unroll
      for (int r = 0; r < 4; ++r) u.s[r] = f2bf(acck[j][i][r]);
      *(uint2*)&Ko[((size_t)(bidx * NH + hh) * TSEQ + tq) * DH + d0] = u.v;
    }
  }
}

// ---------------------------------------------------------------------------
// Kernel 2: flash attention. 64 q-rows per wave (4 q-sets), 256 q per block;
// each K/V LDS fragment feeds 4 MFMA. Double-buffered K/V staging, 1 barrier
// per tile. Softmax exp via fused in-asm exp2pk4 (round-4). jn-split PV
// overlap (round-5). Grid = (64 bh, 8 qblk) = 512 blocks = 2 blocks/CU.
// ---------------------------------------------------------------------------
__global__ __launch_bounds__(256) void flash_attn(
    const int* __restrict__ flag_p, const u16* __restrict__ dout,
    const u16* __restrict__ K, const u16* __restrict__ VT,
    u16* __restrict__ AO)
{
  __shared__ __align__(16) u16 Ks[2][2 * 64 * 32];  // [buf][half][64 keys][32 d]
  __shared__ __align__(16) u16 Vs[2][2 * 64 * 32];  // [buf][half][64 d][32 keys]
  __shared__ __align__(16) u16 Ps[4 * 64 * 72];     // per-wave [64 q][64+8 keys]
  __shared__ float Ls[4 * 64];
  const int flag = *flag_p;
  const u16* __restrict__ QT = flag ? dout : dout + NQ;
  const int t = threadIdx.x;
  const int wave = t >> 6, lane = t & 63;
  const int lr = lane & 15, g = lane >> 4, kg = g * 8;
  const int bh = blockIdx.x;          // fastest grid dim -> XCD = bh % 8
  const int q0 = blockIdx.y * 256;
  const u16* __restrict__ QTh = QT + (size_t)bh * DH * TSEQ;  // [64 d][T]
  const u16* __restrict__ Kh = K + (size_t)bh * TSEQ * DH;
  const u16* __restrict__ Vh = VT + (size_t)bh * DH * TSEQ;

  // 8 Q B-fragments per wave: q-sets s=0..3 (16 q each), d-halves 0/1.
  const int qi = q0 + wave * 64 + lr;
  bf16x8 qf[8];
#pragma unroll
  for (int s = 0; s < 4; ++s) {
    union { u16 v[8]; bf16x8 b; } u0, u1;
#pragma unroll
    for (int j = 0; j < 8; ++j) {
      u0.v[j] = QTh[(size_t)(kg + j) * TSEQ + qi + s * 16];
      u1.v[j] = QTh[(size_t)(32 + kg + j) * TSEQ + qi + s * 16];
    }
    qf[s * 2] = u0.b; qf[s * 2 + 1] = u1.b;
  }

  f32x4 acc[4][4] = {};                 // [set][dn]
  f32x2 ls0[4] = {}, ls1[4] = {};

  const int srow = t >> 2, skc = (t & 3) * 8;
  const u16* kb = Kh + (size_t)srow * DH + skc;
  const u16* vb = Vh + (size_t)srow * TSEQ + skc;
  u16* const pw = &Ps[wave * 64 * 72];  // q-set s at rows s*16..s*16+15

  // prologue: prefetch tile 0 into buffer 0
  gl_lds16(kb,      &Ks[0][t * 8]);          // keys, d 0..31
  gl_lds16(kb + 32, &Ks[0][(t + 256) * 8]);  // keys, d 32..63
  gl_lds16(vb,      &Vs[0][t * 8]);          // [d][keys 0..31]
  gl_lds16(vb + 32, &Vs[0][(t + 256) * 8]);  // [d][keys 32..63]
  kb += 64 * DH; vb += 64;

  int cur = 0;
  for (int j0 = 0; j0 < TSEQ; j0 += 64) {
    // single barrier per tile: drains cur-buf loads (issued a full tile ago)
    // and guarantees everyone is done reading buf^1 before we overwrite it.
    __syncthreads();
    if (j0 + 64 < TSEQ) {
      gl_lds16(kb,      &Ks[cur ^ 1][t * 8]);
      gl_lds16(kb + 32, &Ks[cur ^ 1][(t + 256) * 8]);
      gl_lds16(vb,      &Vs[cur ^ 1][t * 8]);
      gl_lds16(vb + 32, &Vs[cur ^ 1][(t + 256) * 8]);
      kb += 64 * DH; vb += 64;
    }
    const u16* __restrict__ Kc = Ks[cur];
    const u16* __restrict__ Vc = Vs[cur];

    // --- QK key-rows 0..31 (jn = 0,1) ---
#pragma unroll
    for (int jn = 0; jn < 2; ++jn) {
      const bf16x8 kf0 = *(const bf16x8*)&Kc[(jn * 16 + lr) * 32 + kg];
      const bf16x8 kf1 = *(const bf16x8*)&Kc[2048 + (jn * 16 + lr) * 32 + kg];
#pragma unroll
      for (int s = 0; s < 4; ++s) {
        f32x4 sS = {};
        sS = __builtin_amdgcn_mfma_f32_16x16x32_bf16(kf0, qf[s * 2],     sS, 0, 0, 0);
        sS = __builtin_amdgcn_mfma_f32_16x16x32_bf16(kf1, qf[s * 2 + 1], sS, 0, 0, 0);
        float e0, e1, e2, e3;
        uint2 w;
        exp2pk4(sS, e0, e1, e2, e3, w.x, w.y);
        ls0[s] += (f32x2){e0, e1};
        ls1[s] += (f32x2){e2, e3};
        *(uint2*)&pw[s * 16 * 72 + lr * 72 + jn * 16 + g * 4] = w;
      }
    }

    // pf0 (keys 0..31) issued now: in-order DS -> completes after the jn0/1
    // writes (same region) but does NOT wait on the jn2/3 writes below.
    bf16x8 pf0[4];
#pragma unroll
    for (int s = 0; s < 4; ++s)
      pf0[s] = *(const bf16x8*)&pw[s * 16 * 72 + lr * 72 + kg];

    // --- QK key-rows 32..63 (jn = 2,3): VALU here covers pf0 DS latency ---
#pragma unroll
    for (int jn = 2; jn < 4; ++jn) {
      const bf16x8 kf0 = *(const bf16x8*)&Kc[(jn * 16 + lr) * 32 + kg];
      const bf16x8 kf1 = *(const bf16x8*)&Kc[2048 + (jn * 16 + lr) * 32 + kg];
#pragma unroll
      for (int s = 0; s < 4; ++s) {
        f32x4 sS = {};
        sS = __builtin_amdgcn_mfma_f32_16x16x32_bf16(kf0, qf[s * 2],     sS, 0, 0, 0);
        sS = __builtin_amdgcn_mfma_f32_16x16x32_bf16(kf1, qf[s * 2 + 1], sS, 0, 0, 0);
        float e0, e1, e2, e3;
        uint2 w;
        exp2pk4(sS, e0, e1, e2, e3, w.x, w.y);
        ls0[s] += (f32x2){e0, e1};
        ls1[s] += (f32x2){e2, e3};
        *(uint2*)&pw[s * 16 * 72 + lr * 72 + jn * 16 + g * 4] = w;
      }
    }

    // --- PV key-half 0 ---
#pragma unroll
    for (int dn = 0; dn < 4; ++dn) {
      const bf16x8 vf0 = *(const bf16x8*)&Vc[(dn * 16 + lr) * 32 + kg];
#pragma unroll
      for (int s = 0; s < 4; ++s)
        acc[s][dn] = __builtin_amdgcn_mfma_f32_16x16x32_bf16(pf0[s], vf0, acc[s][dn], 0, 0, 0);
    }

    // pf1 (keys 32..63), then PV key-half 1
    bf16x8 pf1[4];
#pragma unroll
    for (int s = 0; s < 4; ++s)
      pf1[s] = *(const bf16x8*)&pw[s * 16 * 72 + lr * 72 + 32 + kg];
#pragma unroll
    for (int dn = 0; dn < 4; ++dn) {
      const bf16x8 vf1 = *(const bf16x8*)&Vc[2048 + (dn * 16 + lr) * 32 + kg];
#pragma unroll
      for (int s = 0; s < 4; ++s)
        acc[s][dn] = __builtin_amdgcn_mfma_f32_16x16x32_bf16(pf1[s], vf1, acc[s][dn], 0, 0, 0);
    }
    cur ^= 1;
  }

  // lsum reductions: lane partial covers key subset for q=lr of each set.
#pragma unroll
  for (int s = 0; s < 4; ++s) {
    float l = (ls0[s][0] + ls0[s][1]) + (ls1[s][0] + ls1[s][1]);
    l += __shfl_xor(l, 16, 64);
    l += __shfl_xor(l, 32, 64);
    Ls[wave * 64 + s * 16 + lr] = l;
  }
  __syncthreads();

  const int bb = bh >> 4, hh = bh & 15;
#pragma unroll
  for (int s = 0; s < 4; ++s) {
#pragma unroll
    for (int r = 0; r < 4; ++r) {
      const int qq = g * 4 + r;
      const float inv = 1.f / fmaxf(Ls[wave * 64 + s * 16 + qq], 1e-30f);
      const int ti = q0 + wave * 64 + s * 16 + qq;
      u16* dst = AO + (((size_t)bb * TSEQ + ti) * NH + hh) * DH + lr;
#pragma unroll
      for (int dn = 0; dn < 4; ++dn)
        dst[dn * 16] = f2bf(acc[s][dn][r] * inv);
    }
  }
}

// ---------------------------------------------------------------------------
// Kernel 3: output projection  out = AO @ Wo^T + bo  (BK=64 two-buffer).
// Raw-Wo read when flag=1. (Round-6: XCD swizzle reverted — it was a no-op
// relabeling; grid-linear already gives each XCD a consistent A-slice.)
// ---------------------------------------------------------------------------
__global__ __launch_bounds__(256) void out_gemm(
    const int* __restrict__ flag_p,
    const u16* __restrict__ A, const u16* __restrict__ W,
    const void* __restrict__ wo_r,
    const void* __restrict__ bias_raw, void* __restrict__ outp)
{
  __shared__ __align__(16) u16 As[2 * 128 * 32];
  __shared__ __align__(16) u16 Bs[2 * 128 * 32];
  const int flag = *flag_p;
  const u16* __restrict__ Wm = flag ? (const u16*)wo_r : W;
  const int t = threadIdx.x;
  const int m0 = blockIdx.x * 128;
  const int n0 = blockIdx.y * 128;
  const int wave = t >> 6, lane = t & 63;
  const int wm = (wave >> 1) * 64, wn = (wave & 1) * 64;
  const int lr = lane & 15, kg = (lane >> 4) * 8;

  const int srow0 = t >> 2, skc = (t & 3) * 8;
  const int srow1 = srow0 + 64;
  const u16* a0 = A + (size_t)(m0 + srow0) * D_MODEL + skc;
  const u16* a1 = A + (size_t)(m0 + srow1) * D_MODEL + skc;
  const u16* b0 = Wm + (size_t)(n0 + srow0) * D_MODEL + skc;
  const u16* b1 = Wm + (size_t)(n0 + srow1) * D_MODEL + skc;

  f32x4 acc[4][4] = {};

  for (int kt = 0; kt < D_MODEL / 64; ++kt) {
    gl_lds16(a0,      &As[t * 8]);
    gl_lds16(a1,      &As[(t + 256) * 8]);
    gl_lds16(a0 + 32, &As[4096 + t * 8]);
    gl_lds16(a1 + 32, &As[4096 + (t + 256) * 8]);
    gl_lds16(b0,      &Bs[t * 8]);
    gl_lds16(b1,      &Bs[(t + 256) * 8]);
    gl_lds16(b0 + 32, &Bs[4096 + t * 8]);
    gl_lds16(b1 + 32, &Bs[4096 + (t + 256) * 8]);
    a0 += 64; a1 += 64; b0 += 64; b1 += 64;
    __syncthreads();
#pragma unroll
    for (int h = 0; h < 2; ++h) {
      bf16x8 af[4], bfr[4];
#pragma unroll
      for (int i = 0; i < 4; ++i)
        af[i] = *(const bf16x8*)&As[h * 4096 + (wm + i * 16 + lr) * 32 + kg];
#pragma unroll
      for (int j = 0; j < 4; ++j)
        bfr[j] = *(const bf16x8*)&Bs[h * 4096 + (wn + j * 16 + lr) * 32 + kg];
#pragma unroll
      for (int i = 0; i < 4; ++i)
#pragma unroll
        for (int j = 0; j < 4; ++j)
          acc[i][j] = __builtin_amdgcn_mfma_f32_16x16x32_bf16(af[i], bfr[j], acc[i][j], 0, 0, 0);
    }
    __syncthreads();
  }

#pragma unroll
  for (int j = 0; j < 4; ++j) {
    const int colg = n0 + wn + j * 16 + lr;
    const float bv = flag ? bf2f(((const u16*)bias_raw)[colg])
                          : ((const float*)bias_raw)[colg];
#pragma unroll
    for (int i = 0; i < 4; ++i) {
      const int rowg = m0 + wm + i * 16 + ((lane >> 4) << 2);
      if (flag) {
        u16* dst = (u16*)outp + (size_t)rowg * D_MODEL + colg;
#pragma unroll
        for (int r = 0; r < 4; ++r)
          dst[(size_t)r * D_MODEL] = f2bf(acc[i][j][r] + bv);
      } else {
        float* dst = (float*)outp + (size_t)rowg * D_MODEL + colg;
#pragma unroll
        for (int r = 0; r < 4; ++r)
          dst[(size_t)r * D_MODEL] = acc[i][j][r] + bv;
      }
    }
  }
}

extern "C" void kernel_launch(void* const* d_in, const int* in_sizes, int n_in,
                              void* d_out, int out_size, void* d_ws, size_t ws_size,
                              hipStream_t stream) {
  const void* x  = d_in[0];
  const void* wq = d_in[1];
  const void* wk = d_in[2];
  const void* wv = d_in[3];
  const void* wo = d_in[4];
  const void* bo = d_in[5];
  u16* dout = (u16*)d_out;

  // ws: [flag 16B][Wq][Wk][Wv][Wo bf16, 2MiB ea][K][VT][AO 16MiB ea]
  int* flag = (int*)d_ws;
  u16* wqb = (u16*)d_ws + 8;
  u16* wkb = wqb + WSZ;
  u16* wvb = wkb + WSZ;
  u16* wob = wvb + WSZ;
  u16* kk  = wob + WSZ;
  u16* vt  = kk + NQ;
  u16* ao  = vt + NQ;

  detect_dtype<<<1, 256, 0, stream>>>((const u32*)wq, flag);

  dim3 gc(NQ / (256 * 8), 5);
  convert_inputs<<<gc, dim3(256), 0, stream>>>(
      x, wq, wk, wv, wo, dout, wqb, wkb, wvb, wob, flag);

  dim3 g1(MTOT / 128, D_MODEL / 128, 1);
  qkv_gemm<<<g1, dim3(256), 0, stream>>>(
      flag, (const u16*)x, dout, wqb, wkb, wvb, wq, wk, wv, kk, vt);

  dim3 g2(BATCH * NH, TSEQ / 256, 1);
  flash_attn<<<g2, dim3(256), 0, stream>>>(flag, dout, kk, vt, ao);

  dim3 g3(MTOT / 128, D_MODEL / 128, 1);
  out_gemm<<<g3, dim3(256), 0, stream>>>(flag, ao, wob, wo, bo, d_out);
}